// Round 13
// baseline (403.331 us; speedup 1.0000x reference)
//
#include <hip/hip_runtime.h>
#include <hip/hip_bf16.h>
#include <hip/hip_fp16.h>
#include <hip/hip_fp8.h>

// GCN: N=100000 nodes, E=1600000 edges, B=64 graphs, 20 -> 128 -> 128 -> 256.
// Strategy:
//  - gcn_conv(h,W) = (scatter_norm(h)) @ W; mean-pool commutes with W3.
//  - R1: segment starts via sorted-batch boundary detection.
//  - R3: CSR build as two-level bucket sort (random scatters live in LDS).
//  - R4-R8: gathers pinned by random per-edge row traversal (width-invariant).
//  - R6: layer2 fused @16 nodes/block, full occ. R7: fp8 payloads.
//  - R9: scatter-pool FAILED (one edge/wave serial). Lesson: edge-parallel.
//  - R11: layer2 GEMM on MFMA (verified B-frag pack = k_packW2 layout).
//  - R12: layer-3 random gather -> dense per-bucket GEMM: pooled += C @ R.
//    C[g][s]=sum(dinv_dst) built edge-parallel via LDS atomics from src-sorted
//    edges; R = 128 sequential h2 rows (fp8->bf16); 32 MFMAs/wave; global
//    atomicAdd out. Replaces ~97us random gather with ~20us dense work.

typedef unsigned short ushort_t;
typedef unsigned int uint_t;
typedef __attribute__((ext_vector_type(8))) short bf16x8;
typedef __attribute__((ext_vector_type(4))) float f32x4;

constexpr int N  = 100000;
constexpr int E  = 1600000;
constexpr int B  = 64;
constexpr int IND = 20;
constexpr int HID = 128;
constexpr int OUTD = 256;

constexpr int NBUK = (N + 127) / 128;   // 782 buckets of 128 nodes
constexpr int GB   = 256;               // hist/scatter blocks
constexpr int EPB  = E / GB;            // 6250 edges per block
constexpr int BMAX = 3072;              // LDS cap per bucket (mean 2048, sd ~45)

// bf16 helpers (RNE pack, shift-unpack)
__device__ inline ushort_t f2bf(float f) {
  union { float f; uint_t u; } v; v.f = f;
  uint_t r = v.u + 0x7fffu + ((v.u >> 16) & 1u);
  return (ushort_t)(r >> 16);
}
__device__ inline float bflo(uint_t u) { return __uint_as_float(u << 16); }
__device__ inline float bfhi(uint_t u) { return __uint_as_float(u & 0xffff0000u); }

// fp8 e4m3 helpers (HW cvt on gfx950; hip_fp8.h fallback)
#if defined(__has_builtin)
#if __has_builtin(__builtin_amdgcn_cvt_f32_fp8) && __has_builtin(__builtin_amdgcn_cvt_pk_fp8_f32)
#define FP8_HW 1
#endif
#endif

template <int S>
__device__ inline float fp8dec(uint_t u) {
#ifdef FP8_HW
  return __builtin_amdgcn_cvt_f32_fp8(u, S);
#else
  __hip_fp8_storage_t b = (__hip_fp8_storage_t)((u >> (8 * S)) & 0xffu);
  __half_raw hr = __hip_cvt_fp8_to_halfraw(b, __HIP_E4M3);
  return __half2float(*(__half*)&hr);
#endif
}

template <bool W>
__device__ inline uint_t fp8pk2(float a, float b, uint_t old) {
#ifdef FP8_HW
  return __builtin_amdgcn_cvt_pk_fp8_f32(a, b, old, W);
#else
  uint_t lo = (uint_t)__hip_cvt_float_to_fp8(a, __HIP_SATFINITE, __HIP_E4M3);
  uint_t hi = (uint_t)__hip_cvt_float_to_fp8(b, __HIP_SATFINITE, __HIP_E4M3);
  uint_t pair = lo | (hi << 8);
  return W ? ((old & 0x0000ffffu) | (pair << 16)) : ((old & 0xffff0000u) | pair);
#endif
}

__device__ inline unsigned char fp8enc1(float a) {
  return (unsigned char)(fp8pk2<false>(a, a, 0u) & 0xffu);
}

// decode 8 fp8 (uint2) into a[0..7]
#define FP8DEC8(u, a0, a1, a2, a3, a4, a5, a6, a7) \
  { a0 = fp8dec<0>(u.x); a1 = fp8dec<1>(u.x); a2 = fp8dec<2>(u.x); a3 = fp8dec<3>(u.x); \
    a4 = fp8dec<0>(u.y); a5 = fp8dec<1>(u.y); a6 = fp8dec<2>(u.y); a7 = fp8dec<3>(u.y); }

// ---------------- init + segment starts ----------------

__global__ __launch_bounds__(256) void k_seg_starts(const int* __restrict__ batch,
                                                    int* __restrict__ starts,
                                                    float* __restrict__ pooled) {
  int i = blockIdx.x * 256 + threadIdx.x;
  if (i < B * HID) pooled[i] = 0.f;
  if (i >= N) return;
  int b = batch[i];
  int prev = (i == 0) ? -1 : batch[i - 1];
  for (int g = prev + 1; g <= b; ++g) starts[g] = i;  // fires only at boundaries
  if (i == N - 1)
    for (int g = b + 1; g <= B; ++g) starts[g] = N;
}

// Pack W2 (fp32 [K=128][N=128]) into bf16 MFMA B-fragment order:
// entry ((t*4+kt)*64 + lane)*8 + j  <-  W[kt*32 + (lane>>4)*8 + j][t*16 + (lane&15)]
__global__ __launch_bounds__(256) void k_packW2(const float* __restrict__ W,
                                                ushort_t* __restrict__ wpack) {
  int idx = blockIdx.x * 256 + threadIdx.x;   // 64 blocks -> 16384 entries
  int j = idx & 7;
  int L = (idx >> 3) & 63;
  int kt = (idx >> 9) & 3;
  int t = idx >> 11;
  int k = kt * 32 + ((L >> 4) & 3) * 8 + j;
  int n = t * 16 + (L & 15);
  wpack[idx] = f2bf(W[k * HID + n]);
}

// ---------------- CSR builds: bucket sorts by dst AND by src ----------------

// One pass builds BOTH histograms (dst>>7 and src>>7).
__global__ __launch_bounds__(256) void k_hist(const int* __restrict__ eidx,
                                              int* __restrict__ histd,
                                              int* __restrict__ hists) {
  __shared__ int hd[NBUK], hs[NBUK];
  for (int i = threadIdx.x; i < NBUK; i += 256) { hd[i] = 0; hs[i] = 0; }
  __syncthreads();
  const long base = (long)blockIdx.x * EPB;
  for (int i = threadIdx.x; i < EPB; i += 256) {
    atomicAdd(&hs[eidx[base + i] >> 7], 1);
    atomicAdd(&hd[eidx[E + base + i] >> 7], 1);
  }
  __syncthreads();
  for (int i = threadIdx.x; i < NBUK; i += 256) {
    histd[(long)blockIdx.x * NBUK + i] = hd[i];
    hists[(long)blockIdx.x * NBUK + i] = hs[i];
  }
}

__global__ __launch_bounds__(256) void k_bscan(int* __restrict__ hist,
                                               int* __restrict__ btotal) {
  __shared__ int s[256];
  const int j = blockIdx.x, tid = threadIdx.x;
  int v = hist[(long)tid * NBUK + j];
  s[tid] = v;
  for (int off = 1; off < 256; off <<= 1) {
    __syncthreads();
    int x = (tid >= off) ? s[tid - off] : 0;
    __syncthreads();
    s[tid] += x;
  }
  hist[(long)tid * NBUK + j] = s[tid] - v;   // exclusive within bucket
  if (tid == 255) btotal[j] = s[255];
}

__global__ __launch_bounds__(256) void k_bktscan(const int* __restrict__ btotal,
                                                 int* __restrict__ bexcl,
                                                 int* __restrict__ rowptr) {
  __shared__ int s[256];
  int tid = threadIdx.x;
  int base = tid * 4;
  int v0 = (base + 0 < NBUK) ? btotal[base + 0] : 0;
  int v1 = (base + 1 < NBUK) ? btotal[base + 1] : 0;
  int v2 = (base + 2 < NBUK) ? btotal[base + 2] : 0;
  int v3 = (base + 3 < NBUK) ? btotal[base + 3] : 0;
  int p0 = v0, p1 = p0 + v1, p2 = p1 + v2, p3 = p2 + v3;
  s[tid] = p3;
  for (int off = 1; off < 256; off <<= 1) {
    __syncthreads();
    int x = (tid >= off) ? s[tid - off] : 0;
    __syncthreads();
    s[tid] += x;
  }
  int excl = s[tid] - p3;
  if (base + 0 < NBUK) bexcl[base + 1] = excl + p0;
  if (base + 1 < NBUK) bexcl[base + 2] = excl + p1;
  if (base + 2 < NBUK) bexcl[base + 3] = excl + p2;
  if (base + 3 < NBUK) bexcl[base + 4] = excl + p3;
  if (tid == 0) { bexcl[0] = 0; rowptr[N] = E; }
}

// dst-order scatter: payload src(20b) | dstlow(7b)<<20
__global__ __launch_bounds__(256) void k_scatter(const int* __restrict__ eidx,
                                                 const int* __restrict__ hist,
                                                 const int* __restrict__ bexcl,
                                                 int* __restrict__ ebuf) {
  __shared__ int h[NBUK];
  for (int i = threadIdx.x; i < NBUK; i += 256)
    h[i] = bexcl[i] + hist[(long)blockIdx.x * NBUK + i];
  __syncthreads();
  const long base = (long)blockIdx.x * EPB;
  for (int i = threadIdx.x; i < EPB; i += 256) {
    int srcv = eidx[base + i];
    int d = eidx[E + base + i];
    int pos = atomicAdd(&h[d >> 7], 1);
    ebuf[pos] = srcv | ((d & 127) << 20);
  }
}

// src-order scatter (AFTER k_csr so dinv ready):
// payload srclow(7b)<<22 | batch[dst](6b)<<16 | bf16(dinv[dst])
__global__ __launch_bounds__(256) void k_scatter2(const int* __restrict__ eidx,
                                                  const int* __restrict__ hist2,
                                                  const int* __restrict__ bexcl2,
                                                  const int* __restrict__ batch,
                                                  const float* __restrict__ dinv,
                                                  int* __restrict__ ebuf2) {
  __shared__ int h[NBUK];
  for (int i = threadIdx.x; i < NBUK; i += 256)
    h[i] = bexcl2[i] + hist2[(long)blockIdx.x * NBUK + i];
  __syncthreads();
  const long base = (long)blockIdx.x * EPB;
  for (int i = threadIdx.x; i < EPB; i += 256) {
    int s = eidx[base + i];
    int d = eidx[E + base + i];
    int pos = atomicAdd(&h[s >> 7], 1);
    int w16 = f2bf(dinv[d]);                  // random 4B reads, 800KB L2-resident
    ebuf2[pos] = ((s & 127) << 22) | (batch[d] << 16) | w16;
  }
}

// One block per dst-bucket: LDS counting sort -> rowptr/dinv/colsrc, plus bf16
// x*dinv table (xs16) for the 20-dim gather.
__global__ __launch_bounds__(256) void k_csr(const int* __restrict__ ebuf,
                                             const int* __restrict__ bexcl,
                                             const float* __restrict__ x,
                                             int* __restrict__ rowptr,
                                             float* __restrict__ dinv,
                                             int* __restrict__ colsrc,
                                             ushort_t* __restrict__ xs16) {
  __shared__ int deg[128], s[128], cur[128];
  __shared__ float dv[128];
  __shared__ int lout[BMAX];
  const int j = blockIdx.x, tid = threadIdx.x;
  const int e0 = bexcl[j], e1 = bexcl[j + 1];
  const int cnt = e1 - e0;
  if (tid < 128) deg[tid] = 0;
  __syncthreads();
  for (int i = tid; i < cnt; i += 256)
    atomicAdd(&deg[(ebuf[e0 + i] >> 20) & 127], 1);
  __syncthreads();
  int v = (tid < 128) ? deg[tid] : 0;
  if (tid < 128) s[tid] = v;
  for (int off = 1; off < 128; off <<= 1) {
    __syncthreads();
    int x2 = (tid < 128 && tid >= off) ? s[tid - off] : 0;
    __syncthreads();
    if (tid < 128) s[tid] += x2;
  }
  __syncthreads();
  if (tid < 128) {
    int ex = s[tid] - v;
    cur[tid] = ex;
    float d = rsqrtf((float)(1 + v));   // deg includes self-loop
    dv[tid] = d;
    int node = j * 128 + tid;
    if (node < N) {
      rowptr[node] = e0 + ex;
      dinv[node] = d;
    }
  }
  __syncthreads();
  if (cnt <= BMAX) {
    for (int i = tid; i < cnt; i += 256) {
      int p = ebuf[e0 + i];
      int pos = atomicAdd(&cur[(p >> 20) & 127], 1);
      lout[pos] = p & 0xFFFFF;
    }
    __syncthreads();
    for (int i = tid; i < cnt; i += 256) colsrc[e0 + i] = lout[i];
  } else {  // safety fallback: direct global scatter (window still tiny -> L2)
    for (int i = tid; i < cnt; i += 256) {
      int p = ebuf[e0 + i];
      int pos = atomicAdd(&cur[(p >> 20) & 127], 1);
      colsrc[e0 + pos] = p & 0xFFFFF;
    }
  }
  // xs16 rows for this bucket (reads x coalesced, L2-warm)
  for (int idx = tid; idx < 128 * IND; idx += 256) {
    int n = idx / IND;
    long node = (long)j * 128 + n;
    if (node < N)
      xs16[node * IND + idx % IND] = f2bf(x[node * IND + idx % IND] * dv[n]);
  }
}

// ---------------- layer 1 ----------------

// 20-dim gather over bf16 x*dinv rows: 10 threads/node, 2 channels each.
__global__ __launch_bounds__(256) void k_gather20b(const ushort_t* __restrict__ xs16,
                                                   const float* __restrict__ dinv,
                                                   const int* __restrict__ rowptr,
                                                   const int* __restrict__ colsrc,
                                                   float* __restrict__ aggx) {
  int t = threadIdx.x;
  if (t >= 250) return;
  int n = t / 10, cc = (t % 10) * 2;
  long i = (long)blockIdx.x * 25 + n;               // grid = N/25 exact
  float di = dinv[i];
  uint_t u = *(const uint_t*)(xs16 + i * IND + cc);
  float a0 = bflo(u), a1 = bfhi(u);
  int e0 = rowptr[i], e1 = rowptr[i + 1];
#pragma unroll 4
  for (int e = e0; e < e1; ++e) {
    int s = colsrc[e];
    uint_t v = *(const uint_t*)(xs16 + (long)s * IND + cc);
    a0 += bflo(v); a1 += bfhi(v);
  }
  *(float2*)&aggx[i * IND + cc] = make_float2(a0 * di, a1 * di);
}

// h1 = relu(LN1(aggx@W1 + b1 + x@resW + resb));
// writes bf16(h1*dinv) (residual source) + fp8(h1*dinv) (gather payload).
__global__ __launch_bounds__(128) void k_conv1ln(const float* __restrict__ aggx,
                                                 const float* __restrict__ x,
                                                 const float* __restrict__ W1,
                                                 const float* __restrict__ b1,
                                                 const float* __restrict__ Wr,
                                                 const float* __restrict__ rb,
                                                 const float* __restrict__ g1,
                                                 const float* __restrict__ bb1,
                                                 const float* __restrict__ dinv,
                                                 ushort_t* __restrict__ h16a,
                                                 unsigned char* __restrict__ h8a) {
  __shared__ float W1s[IND * HID], Wrs[IND * HID], as[16 * IND], xs[16 * IND];
  __shared__ float Tn[16][HID];
  __shared__ float stats[16][2];
  int tid = threadIdx.x;
  for (int i = tid; i < IND * HID; i += 128) { W1s[i] = W1[i]; Wrs[i] = Wr[i]; }
  long node0 = (long)blockIdx.x * 16;                 // grid = N/16 exact
  for (int i = tid; i < 16 * IND; i += 128) {
    as[i] = aggx[node0 * IND + i];
    xs[i] = x[node0 * IND + i];
  }
  float bj = b1[tid] + rb[tid];
  __syncthreads();
  for (int n = 0; n < 16; ++n) {
    float a = bj;
#pragma unroll
    for (int k = 0; k < IND; ++k) {
      a = fmaf(as[n * IND + k], W1s[k * HID + tid], a);
      a = fmaf(xs[n * IND + k], Wrs[k * HID + tid], a);
    }
    Tn[n][tid] = a;
  }
  __syncthreads();
  {
    int n = tid >> 3, sub = tid & 7;    // 8 threads per node
    float s = 0.f, q = 0.f;
#pragma unroll
    for (int k = sub; k < HID; k += 8) { float v2 = Tn[n][k]; s += v2; q += v2 * v2; }
    s += __shfl_xor(s, 1); q += __shfl_xor(q, 1);
    s += __shfl_xor(s, 2); q += __shfl_xor(q, 2);
    s += __shfl_xor(s, 4); q += __shfl_xor(q, 4);
    if (sub == 0) {
      float mu = s * (1.f / 128.f);
      float var = q * (1.f / 128.f) - mu * mu;
      stats[n][0] = mu;
      stats[n][1] = rsqrtf(var + 1e-5f);
    }
  }
  __syncthreads();
  float gj = g1[tid], bbj = bb1[tid];
  for (int n = 0; n < 16; ++n) {
    float mu = stats[n][0], rs = stats[n][1];
    float y = fmaxf(fmaf((Tn[n][tid] - mu) * rs, gj, bbj), 0.f);
    float yd = y * dinv[node0 + n];
    h16a[(node0 + n) * HID + tid] = f2bf(yd);
    h8a[(node0 + n) * HID + tid] = fp8enc1(yd);
  }
}

// ---------------- layer 2: fp8 gather + MFMA GEMM + LN + ReLU ----------------

constexpr int XSTR = 136;   // bf16 stride (pad kills stride-128 bank aliasing)
constexpr int CSTR = 132;   // fp32 C stride

__global__ __launch_bounds__(256) void k_layer2(const unsigned char* __restrict__ h8a,
                                                const ushort_t* __restrict__ h16a,
                                                const float* __restrict__ dinv,
                                                const int* __restrict__ rowptr,
                                                const int* __restrict__ colsrc,
                                                const ushort_t* __restrict__ wpack,
                                                const float* __restrict__ bias,
                                                const float* __restrict__ g2,
                                                const float* __restrict__ bb2,
                                                unsigned char* __restrict__ h8b) {
  __shared__ ushort_t XsB[16 * XSTR];   // 4.25 KB bf16 gathered X
  __shared__ float Cs[16 * CSTR];       // 8.25 KB fp32 GEMM out
  const int tid = threadIdx.x;
  const long node0 = (long)blockIdx.x * 16;           // grid = N/16 exact
  const int lane = tid & 63, w = tid >> 6;
  const int grp = lane >> 4, l16 = lane & 15, c = l16 * 8;
  // ---- phase 1: each wave gathers 4 rows (fp8, 8B/lane), bf16 into XsB ----
  for (int r = 0; r < 4; ++r) {
    const long i = node0 + w * 4 + r;
    const float di = dinv[i];
    float a0 = 0, a1 = 0, a2 = 0, a3 = 0, a4 = 0, a5 = 0, a6 = 0, a7 = 0;
    if (grp == 0) {     // self term (row already carries dinv[i])
      uint2 u = *(const uint2*)(h8a + i * HID + c);
      FP8DEC8(u, a0, a1, a2, a3, a4, a5, a6, a7);
    }
    const int e0 = rowptr[i], e1 = rowptr[i + 1];
#pragma unroll 2
    for (int e = e0; e < e1; e += 4) {
      int idx = e + grp;
      bool valid = idx < e1;
      int s = colsrc[valid ? idx : e];
      uint2 u = *(const uint2*)(h8a + (long)s * HID + c);
      if (valid) {
        float b0, b1, b2, b3, b4, b5, b6, b7;
        FP8DEC8(u, b0, b1, b2, b3, b4, b5, b6, b7);
        a0 += b0; a1 += b1; a2 += b2; a3 += b3;
        a4 += b4; a5 += b5; a6 += b6; a7 += b7;
      }
    }
    a0 += __shfl_xor(a0, 16); a0 += __shfl_xor(a0, 32);
    a1 += __shfl_xor(a1, 16); a1 += __shfl_xor(a1, 32);
    a2 += __shfl_xor(a2, 16); a2 += __shfl_xor(a2, 32);
    a3 += __shfl_xor(a3, 16); a3 += __shfl_xor(a3, 32);
    a4 += __shfl_xor(a4, 16); a4 += __shfl_xor(a4, 32);
    a5 += __shfl_xor(a5, 16); a5 += __shfl_xor(a5, 32);
    a6 += __shfl_xor(a6, 16); a6 += __shfl_xor(a6, 32);
    a7 += __shfl_xor(a7, 16); a7 += __shfl_xor(a7, 32);
    if (grp == 0) {
      uint_t p0 = (uint_t)f2bf(a0 * di) | ((uint_t)f2bf(a1 * di) << 16);
      uint_t p1 = (uint_t)f2bf(a2 * di) | ((uint_t)f2bf(a3 * di) << 16);
      uint_t p2 = (uint_t)f2bf(a4 * di) | ((uint_t)f2bf(a5 * di) << 16);
      uint_t p3 = (uint_t)f2bf(a6 * di) | ((uint_t)f2bf(a7 * di) << 16);
      *(uint4*)&XsB[(w * 4 + r) * XSTR + c] = make_uint4(p0, p1, p2, p3);
    }
  }
  __syncthreads();
  // ---- phase 2: MFMA. Wave w covers n-tiles {2w, 2w+1}. ----
  {
    const int arow = lane & 15, aq = lane >> 4;
    f32x4 acc0 = {0.f, 0.f, 0.f, 0.f}, acc1 = {0.f, 0.f, 0.f, 0.f};
    const int t0 = w * 2, t1 = w * 2 + 1;
#pragma unroll
    for (int kt = 0; kt < 4; ++kt) {
      bf16x8 af = *(const bf16x8*)&XsB[arow * XSTR + kt * 32 + aq * 8];
      bf16x8 b0 = *(const bf16x8*)&wpack[(t0 * 4 + kt) * 512 + lane * 8];
      bf16x8 b1 = *(const bf16x8*)&wpack[(t1 * 4 + kt) * 512 + lane * 8];
      acc0 = __builtin_amdgcn_mfma_f32_16x16x32_bf16(af, b0, acc0, 0, 0, 0);
      acc1 = __builtin_amdgcn_mfma_f32_16x16x32_bf16(af, b1, acc1, 0, 0, 0);
    }
#pragma unroll
    for (int r = 0; r < 4; ++r) {
      Cs[(aq * 4 + r) * CSTR + t0 * 16 + arow] = acc0[r];
      Cs[(aq * 4 + r) * CSTR + t1 * 16 + arow] = acc1[r];
    }
  }
  __syncthreads();
  // ---- phase 3: bias + residual(bf16 h16a) + LN + ReLU + fp8 store ----
  const int nidx = tid >> 5;          // 8 nodes in flight
  const int col = (tid & 31) * 4;     // 32 threads cover 128 cols
  float4 bz = *(const float4*)&bias[col];
  float4 gz = *(const float4*)&g2[col];
  float4 bbz = *(const float4*)&bb2[col];
#pragma unroll
  for (int m = 0; m < 2; ++m) {
    int nl = nidx + m * 8;
    long nm = node0 + nl;
    float di = dinv[nm];
    float rdi = 1.0f / di;
    uint2 ur = *(const uint2*)&h16a[nm * HID + col];
    float4 o = *(const float4*)&Cs[nl * CSTR + col];
    o.x += bz.x + bflo(ur.x) * rdi; o.y += bz.y + bfhi(ur.x) * rdi;
    o.z += bz.z + bflo(ur.y) * rdi; o.w += bz.w + bfhi(ur.y) * rdi;
    float s = o.x + o.y + o.z + o.w;
    float q = o.x * o.x + o.y * o.y + o.z * o.z + o.w * o.w;
#pragma unroll
    for (int off = 1; off <= 16; off <<= 1) {   // 32-lane group = one row
      s += __shfl_xor(s, off);
      q += __shfl_xor(q, off);
    }
    float mu = s * (1.f / 128.f);
    float var = q * (1.f / 128.f) - mu * mu;
    float rs = rsqrtf(var + 1e-5f);
    float y0 = fmaxf(fmaf((o.x - mu) * rs, gz.x, bbz.x), 0.f);
    float y1 = fmaxf(fmaf((o.y - mu) * rs, gz.y, bbz.y), 0.f);
    float y2 = fmaxf(fmaf((o.z - mu) * rs, gz.z, bbz.z), 0.f);
    float y3 = fmaxf(fmaf((o.w - mu) * rs, gz.w, bbz.w), 0.f);
    uint_t p = fp8pk2<false>(y0 * di, y1 * di, 0u);
    p = fp8pk2<true>(y2 * di, y3 * di, p);
    *(uint_t*)&h8b[nm * HID + col] = p;
  }
}

// ---------------- layer 3: per-bucket dense pool GEMM (NO random reads) ----------------

// pooled[g][ch] += sum_s C[g][s] * R[s][ch], per 128-src bucket.
// C built edge-parallel from src-sorted edges; R = sequential h8b rows.
constexpr int RSTR = 136;   // bf16 row stride for R (16B-aligned rows)
constexpr int CP   = 132;   // fp32 row stride for C (16B-aligned, bank-shifted)

__global__ __launch_bounds__(256) void k_pool3m(const unsigned char* __restrict__ h8b,
                                                const int* __restrict__ bexcl2,
                                                const int* __restrict__ ebuf2,
                                                const int* __restrict__ batch,
                                                const float* __restrict__ dinv,
                                                float* __restrict__ pooled) {
  __shared__ float Cm[B * CP];          // 33.8 KB
  __shared__ ushort_t R[128 * RSTR];    // 34.8 KB
  const int j = blockIdx.x, tid = threadIdx.x;
  const long nbase = (long)j * 128;
  const int validRows = min(128, N - (int)nbase);
  // zero C; stage R (fp8 -> bf16, invalid rows zeroed: NaN*0 hazard)
  for (int i = tid; i < B * CP; i += 256) Cm[i] = 0.f;
  for (int i = tid; i < 128 * (HID / 8); i += 256) {
    int s = i >> 4;
    int ch = (i & 15) * 8;
    uint4 pk = make_uint4(0u, 0u, 0u, 0u);
    if (s < validRows) {
      uint2 u = *(const uint2*)(h8b + (nbase + s) * HID + ch);
      float b0, b1, b2, b3, b4, b5, b6, b7;
      FP8DEC8(u, b0, b1, b2, b3, b4, b5, b6, b7);
      pk.x = (uint_t)f2bf(b0) | ((uint_t)f2bf(b1) << 16);
      pk.y = (uint_t)f2bf(b2) | ((uint_t)f2bf(b3) << 16);
      pk.z = (uint_t)f2bf(b4) | ((uint_t)f2bf(b5) << 16);
      pk.w = (uint_t)f2bf(b6) | ((uint_t)f2bf(b7) << 16);
    }
    *(uint4*)&R[s * RSTR + ch] = pk;
  }
  __syncthreads();
  // edge-parallel C build: ~8.5 iters/thread (R9 lesson: parallelize edges)
  const int e0 = bexcl2[j], e1 = bexcl2[j + 1];
  for (int e = e0 + tid; e < e1; e += 256) {
    int p = ebuf2[e];
    int s = (p >> 22) & 127;
    int g = (p >> 16) & 63;
    float wgt = __uint_as_float((uint_t)(p & 0xffff) << 16);   // bf16 dinv[dst]
    atomicAdd(&Cm[g * CP + s], wgt);
  }
  for (int n = tid; n < validRows; n += 256) {
    long node = nbase + n;
    atomicAdd(&Cm[batch[node] * CP + n], dinv[node]);   // self term, exact fp32
  }
  __syncthreads();
  // MFMA: M=64 (g, 4 mtiles), N=128 (ch, 8 ntiles: wave wid gets 2), K=128 (s)
  const int lane = tid & 63, wid = tid >> 6;
  const int m16 = lane & 15, quad = lane >> 4;
  f32x4 acc[4][2];
#pragma unroll
  for (int mt = 0; mt < 4; ++mt)
#pragma unroll
    for (int ntl = 0; ntl < 2; ++ntl) acc[mt][ntl] = (f32x4){0.f, 0.f, 0.f, 0.f};
#pragma unroll
  for (int kt = 0; kt < 4; ++kt) {
    union { ushort_t u[8]; bf16x8 v; } bf[2];
#pragma unroll
    for (int ntl = 0; ntl < 2; ++ntl) {
      int nt = wid * 2 + ntl;
#pragma unroll
      for (int jj = 0; jj < 8; ++jj)
        bf[ntl].u[jj] = R[(kt * 32 + quad * 8 + jj) * RSTR + nt * 16 + m16];
    }
#pragma unroll
    for (int mt = 0; mt < 4; ++mt) {
      float4 c0 = *(const float4*)&Cm[(mt * 16 + m16) * CP + kt * 32 + quad * 8];
      float4 c1 = *(const float4*)&Cm[(mt * 16 + m16) * CP + kt * 32 + quad * 8 + 4];
      union { ushort_t u[8]; bf16x8 v; } af;
      af.u[0] = f2bf(c0.x); af.u[1] = f2bf(c0.y);
      af.u[2] = f2bf(c0.z); af.u[3] = f2bf(c0.w);
      af.u[4] = f2bf(c1.x); af.u[5] = f2bf(c1.y);
      af.u[6] = f2bf(c1.z); af.u[7] = f2bf(c1.w);
      acc[mt][0] = __builtin_amdgcn_mfma_f32_16x16x32_bf16(af.v, bf[0].v, acc[mt][0], 0, 0, 0);
      acc[mt][1] = __builtin_amdgcn_mfma_f32_16x16x32_bf16(af.v, bf[1].v, acc[mt][1], 0, 0, 0);
    }
  }
  // D: col = lane&15 (n), row = quad*4 + r (m). Global atomic accumulate.
#pragma unroll
  for (int mt = 0; mt < 4; ++mt)
#pragma unroll
    for (int ntl = 0; ntl < 2; ++ntl)
#pragma unroll
      for (int r = 0; r < 4; ++r) {
        int g = mt * 16 + quad * 4 + r;
        int ch = (wid * 2 + ntl) * 16 + m16;
        atomicAdd(&pooled[g * HID + ch], acc[mt][ntl][r]);
      }
}

// ---------------- final GEMM ----------------

// out[g] = (pooled[g]/cnt) @ W3 + b3
__global__ __launch_bounds__(256) void k_final(const float* __restrict__ pooled,
                                               const int* __restrict__ starts,
                                               const float* __restrict__ W3,
                                               const float* __restrict__ b3,
                                               float* __restrict__ out) {
  __shared__ float p[HID];
  int g = blockIdx.x, tid = threadIdx.x;
  int len = starts[g + 1] - starts[g];
  float scale = 1.0f / fmaxf((float)len, 1.0f);
  if (tid < HID) p[tid] = pooled[g * HID + tid] * scale;
  __syncthreads();
  float a = b3[tid];
  for (int k = 0; k < HID; ++k) a = fmaf(p[k], W3[k * OUTD + tid], a);
  out[g * OUTD + tid] = a;
}

// ---------------- launch ----------------

extern "C" void kernel_launch(void* const* d_in, const int* in_sizes, int n_in,
                              void* d_out, int out_size, void* d_ws, size_t ws_size,
                              hipStream_t stream) {
  const float* x    = (const float*)d_in[0];
  const int*   eidx = (const int*)d_in[1];
  const int*   batch= (const int*)d_in[2];
  const float* W1   = (const float*)d_in[3];
  const float* b1   = (const float*)d_in[4];
  const float* W2   = (const float*)d_in[5];
  const float* b2   = (const float*)d_in[6];
  const float* W3   = (const float*)d_in[7];
  const float* b3   = (const float*)d_in[8];
  const float* resW = (const float*)d_in[9];
  const float* resb = (const float*)d_in[10];
  const float* g1   = (const float*)d_in[11];
  const float* bb1  = (const float*)d_in[12];
  const float* g2   = (const float*)d_in[13];
  const float* bb2  = (const float*)d_in[14];
  float* out = (float*)d_out;

  char* w = (char*)d_ws;
  size_t off = 0;
  auto alloc = [&](size_t bytes) {
    char* p = w + off;
    off = (off + bytes + 1023) & ~(size_t)1023;
    return p;
  };
  float* dinv   = (float*)alloc((size_t)N * 4);
  int*   rowptr = (int*)alloc((size_t)(N + 1) * 4);
  int*   colsrc = (int*)alloc((size_t)E * 4);
  int*   ebuf   = (int*)alloc((size_t)E * 4);
  int*   ebuf2  = (int*)alloc((size_t)E * 4);
  int*   hist   = (int*)alloc((size_t)GB * NBUK * 4);
  int*   hist2  = (int*)alloc((size_t)GB * NBUK * 4);
  int*   btotal = (int*)alloc((size_t)NBUK * 4);
  int*   btotal2= (int*)alloc((size_t)NBUK * 4);
  int*   bexcl  = (int*)alloc((size_t)(NBUK + 1) * 4);
  int*   bexcl2 = (int*)alloc((size_t)(NBUK + 1) * 4);
  int*   starts = (int*)alloc((size_t)(B + 1) * 4);
  float* pooled = (float*)alloc((size_t)B * HID * 4);
  float* aggx   = (float*)alloc((size_t)N * IND * 4);
  ushort_t* h16a= (ushort_t*)alloc((size_t)N * HID * 2);
  ushort_t* xs16= (ushort_t*)alloc((size_t)N * IND * 2);
  ushort_t* wpack=(ushort_t*)alloc((size_t)HID * HID * 2);
  unsigned char* h8a = (unsigned char*)alloc((size_t)N * HID);
  unsigned char* h8b = (unsigned char*)alloc((size_t)N * HID);

  // ---- CSR builds (dst + src order) + norm + starts + xs16 + W2 pack ----
  k_seg_starts<<<(N + 255) / 256, 256, 0, stream>>>(batch, starts, pooled);
  k_packW2<<<64, 256, 0, stream>>>(W2, wpack);
  k_hist<<<GB, 256, 0, stream>>>(eidx, hist, hist2);
  k_bscan<<<NBUK, 256, 0, stream>>>(hist, btotal);
  k_bscan<<<NBUK, 256, 0, stream>>>(hist2, btotal2);
  k_bktscan<<<1, 256, 0, stream>>>(btotal, bexcl, rowptr);
  k_bktscan<<<1, 256, 0, stream>>>(btotal2, bexcl2, rowptr);
  k_scatter<<<GB, 256, 0, stream>>>(eidx, hist, bexcl, ebuf);
  k_csr<<<NBUK, 256, 0, stream>>>(ebuf, bexcl, x, rowptr, dinv, colsrc, xs16);
  k_scatter2<<<GB, 256, 0, stream>>>(eidx, hist2, bexcl2, batch, dinv, ebuf2);

  // ---- layer 1: 20-dim gather, conv1 + LN1 + ReLU (bf16 + fp8 out) ----
  k_gather20b<<<N / 25, 256, 0, stream>>>(xs16, dinv, rowptr, colsrc, aggx);
  k_conv1ln<<<N / 16, 128, 0, stream>>>(aggx, x, W1, b1, resW, resb,
                                        g1, bb1, dinv, h16a, h8a);

  // ---- layer 2: fp8 gather + MFMA GEMM + LN2 + ReLU (fused), fp8 out ----
  k_layer2<<<N / 16, 256, 0, stream>>>(h8a, h16a, dinv, rowptr, colsrc,
                                       wpack, b2, g2, bb2, h8b);

  // ---- layer 3: dense per-bucket pool GEMM, then 64x128x256 ----
  k_pool3m<<<NBUK, 256, 0, stream>>>(h8b, bexcl2, ebuf2, batch, dinv, pooled);
  k_final<<<B, 256, 0, stream>>>(pooled, starts, W3, b3, out);
}

// Round 14
// 393.047 us; speedup vs baseline: 1.0262x; 1.0262x over previous
//
#include <hip/hip_runtime.h>
#include <hip/hip_bf16.h>
#include <hip/hip_fp16.h>
#include <hip/hip_fp8.h>

// GCN: N=100000 nodes, E=1600000 edges, B=64 graphs, 20 -> 128 -> 128 -> 256.
// Strategy:
//  - gcn_conv(h,W) = (scatter_norm(h)) @ W; mean-pool commutes with W3.
//  - R1: segment starts via sorted-batch boundary detection.
//  - R3: CSR build as two-level bucket sort (random scatters live in LDS).
//  - R4-R8: gathers pinned by random per-edge row traversal (width-invariant).
//  - R6/R7: fused layer2 @16 nodes/block; fp8 payloads.
//  - R9: lesson: edge-parallel scatter or bust. R11: layer2 GEMM on MFMA.
//  - R12: layer-3 -> dense per-bucket GEMM pooled += C @ R. Worked, but output
//    used 6.4M global atomics into 8192 addrs (512 lines) -> serialized (~60us),
//    and the second scatter pass cost ~35us.
//  - R13: (a) pool3m writes per-bucket partial slabs (plain stores; 25.6MB
//    aliased on dead h16a/xs16) + k_pool_reduce sums them; (b) both edge
//    scatters merged into ONE pass (ebuf2 = srclow|dst; dinv/batch lookups
//    deferred to pool3m's C-build, L2-resident).

typedef unsigned short ushort_t;
typedef unsigned int uint_t;
typedef __attribute__((ext_vector_type(8))) short bf16x8;
typedef __attribute__((ext_vector_type(4))) float f32x4;

constexpr int N  = 100000;
constexpr int E  = 1600000;
constexpr int B  = 64;
constexpr int IND = 20;
constexpr int HID = 128;
constexpr int OUTD = 256;

constexpr int NBUK = (N + 127) / 128;   // 782 buckets of 128 nodes
constexpr int GB   = 256;               // hist/scatter blocks
constexpr int EPB  = E / GB;            // 6250 edges per block
constexpr int BMAX = 3072;              // LDS cap per bucket (mean 2048, sd ~45)

// bf16 helpers (RNE pack, shift-unpack)
__device__ inline ushort_t f2bf(float f) {
  union { float f; uint_t u; } v; v.f = f;
  uint_t r = v.u + 0x7fffu + ((v.u >> 16) & 1u);
  return (ushort_t)(r >> 16);
}
__device__ inline float bflo(uint_t u) { return __uint_as_float(u << 16); }
__device__ inline float bfhi(uint_t u) { return __uint_as_float(u & 0xffff0000u); }

// fp8 e4m3 helpers (HW cvt on gfx950; hip_fp8.h fallback)
#if defined(__has_builtin)
#if __has_builtin(__builtin_amdgcn_cvt_f32_fp8) && __has_builtin(__builtin_amdgcn_cvt_pk_fp8_f32)
#define FP8_HW 1
#endif
#endif

template <int S>
__device__ inline float fp8dec(uint_t u) {
#ifdef FP8_HW
  return __builtin_amdgcn_cvt_f32_fp8(u, S);
#else
  __hip_fp8_storage_t b = (__hip_fp8_storage_t)((u >> (8 * S)) & 0xffu);
  __half_raw hr = __hip_cvt_fp8_to_halfraw(b, __HIP_E4M3);
  return __half2float(*(__half*)&hr);
#endif
}

template <bool W>
__device__ inline uint_t fp8pk2(float a, float b, uint_t old) {
#ifdef FP8_HW
  return __builtin_amdgcn_cvt_pk_fp8_f32(a, b, old, W);
#else
  uint_t lo = (uint_t)__hip_cvt_float_to_fp8(a, __HIP_SATFINITE, __HIP_E4M3);
  uint_t hi = (uint_t)__hip_cvt_float_to_fp8(b, __HIP_SATFINITE, __HIP_E4M3);
  uint_t pair = lo | (hi << 8);
  return W ? ((old & 0x0000ffffu) | (pair << 16)) : ((old & 0xffff0000u) | pair);
#endif
}

__device__ inline unsigned char fp8enc1(float a) {
  return (unsigned char)(fp8pk2<false>(a, a, 0u) & 0xffu);
}

// decode 8 fp8 (uint2) into a[0..7]
#define FP8DEC8(u, a0, a1, a2, a3, a4, a5, a6, a7) \
  { a0 = fp8dec<0>(u.x); a1 = fp8dec<1>(u.x); a2 = fp8dec<2>(u.x); a3 = fp8dec<3>(u.x); \
    a4 = fp8dec<0>(u.y); a5 = fp8dec<1>(u.y); a6 = fp8dec<2>(u.y); a7 = fp8dec<3>(u.y); }

// ---------------- init + segment starts ----------------

__global__ __launch_bounds__(256) void k_seg_starts(const int* __restrict__ batch,
                                                    int* __restrict__ starts) {
  int i = blockIdx.x * 256 + threadIdx.x;
  if (i >= N) return;
  int b = batch[i];
  int prev = (i == 0) ? -1 : batch[i - 1];
  for (int g = prev + 1; g <= b; ++g) starts[g] = i;  // fires only at boundaries
  if (i == N - 1)
    for (int g = b + 1; g <= B; ++g) starts[g] = N;
}

// Pack W2 (fp32 [K=128][N=128]) into bf16 MFMA B-fragment order:
// entry ((t*4+kt)*64 + lane)*8 + j  <-  W[kt*32 + (lane>>4)*8 + j][t*16 + (lane&15)]
__global__ __launch_bounds__(256) void k_packW2(const float* __restrict__ W,
                                                ushort_t* __restrict__ wpack) {
  int idx = blockIdx.x * 256 + threadIdx.x;   // 64 blocks -> 16384 entries
  int j = idx & 7;
  int L = (idx >> 3) & 63;
  int kt = (idx >> 9) & 3;
  int t = idx >> 11;
  int k = kt * 32 + ((L >> 4) & 3) * 8 + j;
  int n = t * 16 + (L & 15);
  wpack[idx] = f2bf(W[k * HID + n]);
}

// ---------------- CSR builds: bucket sorts by dst AND by src ----------------

// One pass builds BOTH histograms (dst>>7 and src>>7).
__global__ __launch_bounds__(256) void k_hist(const int* __restrict__ eidx,
                                              int* __restrict__ histd,
                                              int* __restrict__ hists) {
  __shared__ int hd[NBUK], hs[NBUK];
  for (int i = threadIdx.x; i < NBUK; i += 256) { hd[i] = 0; hs[i] = 0; }
  __syncthreads();
  const long base = (long)blockIdx.x * EPB;
  for (int i = threadIdx.x; i < EPB; i += 256) {
    atomicAdd(&hs[eidx[base + i] >> 7], 1);
    atomicAdd(&hd[eidx[E + base + i] >> 7], 1);
  }
  __syncthreads();
  for (int i = threadIdx.x; i < NBUK; i += 256) {
    histd[(long)blockIdx.x * NBUK + i] = hd[i];
    hists[(long)blockIdx.x * NBUK + i] = hs[i];
  }
}

__global__ __launch_bounds__(256) void k_bscan(int* __restrict__ hist,
                                               int* __restrict__ btotal) {
  __shared__ int s[256];
  const int j = blockIdx.x, tid = threadIdx.x;
  int v = hist[(long)tid * NBUK + j];
  s[tid] = v;
  for (int off = 1; off < 256; off <<= 1) {
    __syncthreads();
    int x = (tid >= off) ? s[tid - off] : 0;
    __syncthreads();
    s[tid] += x;
  }
  hist[(long)tid * NBUK + j] = s[tid] - v;   // exclusive within bucket
  if (tid == 255) btotal[j] = s[255];
}

__global__ __launch_bounds__(256) void k_bktscan(const int* __restrict__ btotal,
                                                 int* __restrict__ bexcl,
                                                 int* __restrict__ rowptr) {
  __shared__ int s[256];
  int tid = threadIdx.x;
  int base = tid * 4;
  int v0 = (base + 0 < NBUK) ? btotal[base + 0] : 0;
  int v1 = (base + 1 < NBUK) ? btotal[base + 1] : 0;
  int v2 = (base + 2 < NBUK) ? btotal[base + 2] : 0;
  int v3 = (base + 3 < NBUK) ? btotal[base + 3] : 0;
  int p0 = v0, p1 = p0 + v1, p2 = p1 + v2, p3 = p2 + v3;
  s[tid] = p3;
  for (int off = 1; off < 256; off <<= 1) {
    __syncthreads();
    int x = (tid >= off) ? s[tid - off] : 0;
    __syncthreads();
    s[tid] += x;
  }
  int excl = s[tid] - p3;
  if (base + 0 < NBUK) bexcl[base + 1] = excl + p0;
  if (base + 1 < NBUK) bexcl[base + 2] = excl + p1;
  if (base + 2 < NBUK) bexcl[base + 3] = excl + p2;
  if (base + 3 < NBUK) bexcl[base + 4] = excl + p3;
  if (tid == 0) { bexcl[0] = 0; rowptr[N] = E; }
}

// Merged scatter: ONE edge pass writes BOTH orderings.
// ebuf (dst-order):  src(20b) | dstlow(7b)<<20
// ebuf2 (src-order): srclow(7b)<<17 | dst(17b)   (dinv/batch deferred to pool)
__global__ __launch_bounds__(256) void k_scatter(const int* __restrict__ eidx,
                                                 const int* __restrict__ histd,
                                                 const int* __restrict__ bexcl,
                                                 const int* __restrict__ hists,
                                                 const int* __restrict__ bexcl2,
                                                 int* __restrict__ ebuf,
                                                 int* __restrict__ ebuf2) {
  __shared__ int hd[NBUK], hs[NBUK];
  for (int i = threadIdx.x; i < NBUK; i += 256) {
    hd[i] = bexcl[i] + histd[(long)blockIdx.x * NBUK + i];
    hs[i] = bexcl2[i] + hists[(long)blockIdx.x * NBUK + i];
  }
  __syncthreads();
  const long base = (long)blockIdx.x * EPB;
  for (int i = threadIdx.x; i < EPB; i += 256) {
    int s = eidx[base + i];
    int d = eidx[E + base + i];
    int pos = atomicAdd(&hd[d >> 7], 1);
    ebuf[pos] = s | ((d & 127) << 20);
    int pos2 = atomicAdd(&hs[s >> 7], 1);
    ebuf2[pos2] = ((s & 127) << 17) | d;
  }
}

// One block per dst-bucket: LDS counting sort -> rowptr/dinv/colsrc, plus bf16
// x*dinv table (xs16) for the 20-dim gather.
__global__ __launch_bounds__(256) void k_csr(const int* __restrict__ ebuf,
                                             const int* __restrict__ bexcl,
                                             const float* __restrict__ x,
                                             int* __restrict__ rowptr,
                                             float* __restrict__ dinv,
                                             int* __restrict__ colsrc,
                                             ushort_t* __restrict__ xs16) {
  __shared__ int deg[128], s[128], cur[128];
  __shared__ float dv[128];
  __shared__ int lout[BMAX];
  const int j = blockIdx.x, tid = threadIdx.x;
  const int e0 = bexcl[j], e1 = bexcl[j + 1];
  const int cnt = e1 - e0;
  if (tid < 128) deg[tid] = 0;
  __syncthreads();
  for (int i = tid; i < cnt; i += 256)
    atomicAdd(&deg[(ebuf[e0 + i] >> 20) & 127], 1);
  __syncthreads();
  int v = (tid < 128) ? deg[tid] : 0;
  if (tid < 128) s[tid] = v;
  for (int off = 1; off < 128; off <<= 1) {
    __syncthreads();
    int x2 = (tid < 128 && tid >= off) ? s[tid - off] : 0;
    __syncthreads();
    if (tid < 128) s[tid] += x2;
  }
  __syncthreads();
  if (tid < 128) {
    int ex = s[tid] - v;
    cur[tid] = ex;
    float d = rsqrtf((float)(1 + v));   // deg includes self-loop
    dv[tid] = d;
    int node = j * 128 + tid;
    if (node < N) {
      rowptr[node] = e0 + ex;
      dinv[node] = d;
    }
  }
  __syncthreads();
  if (cnt <= BMAX) {
    for (int i = tid; i < cnt; i += 256) {
      int p = ebuf[e0 + i];
      int pos = atomicAdd(&cur[(p >> 20) & 127], 1);
      lout[pos] = p & 0xFFFFF;
    }
    __syncthreads();
    for (int i = tid; i < cnt; i += 256) colsrc[e0 + i] = lout[i];
  } else {  // safety fallback: direct global scatter (window still tiny -> L2)
    for (int i = tid; i < cnt; i += 256) {
      int p = ebuf[e0 + i];
      int pos = atomicAdd(&cur[(p >> 20) & 127], 1);
      colsrc[e0 + pos] = p & 0xFFFFF;
    }
  }
  // xs16 rows for this bucket (reads x coalesced, L2-warm)
  for (int idx = tid; idx < 128 * IND; idx += 256) {
    int n = idx / IND;
    long node = (long)j * 128 + n;
    if (node < N)
      xs16[node * IND + idx % IND] = f2bf(x[node * IND + idx % IND] * dv[n]);
  }
}

// ---------------- layer 1 ----------------

// 20-dim gather over bf16 x*dinv rows: 10 threads/node, 2 channels each.
__global__ __launch_bounds__(256) void k_gather20b(const ushort_t* __restrict__ xs16,
                                                   const float* __restrict__ dinv,
                                                   const int* __restrict__ rowptr,
                                                   const int* __restrict__ colsrc,
                                                   float* __restrict__ aggx) {
  int t = threadIdx.x;
  if (t >= 250) return;
  int n = t / 10, cc = (t % 10) * 2;
  long i = (long)blockIdx.x * 25 + n;               // grid = N/25 exact
  float di = dinv[i];
  uint_t u = *(const uint_t*)(xs16 + i * IND + cc);
  float a0 = bflo(u), a1 = bfhi(u);
  int e0 = rowptr[i], e1 = rowptr[i + 1];
#pragma unroll 4
  for (int e = e0; e < e1; ++e) {
    int s = colsrc[e];
    uint_t v = *(const uint_t*)(xs16 + (long)s * IND + cc);
    a0 += bflo(v); a1 += bfhi(v);
  }
  *(float2*)&aggx[i * IND + cc] = make_float2(a0 * di, a1 * di);
}

// h1 = relu(LN1(aggx@W1 + b1 + x@resW + resb));
// writes bf16(h1*dinv) (residual source) + fp8(h1*dinv) (gather payload).
__global__ __launch_bounds__(128) void k_conv1ln(const float* __restrict__ aggx,
                                                 const float* __restrict__ x,
                                                 const float* __restrict__ W1,
                                                 const float* __restrict__ b1,
                                                 const float* __restrict__ Wr,
                                                 const float* __restrict__ rb,
                                                 const float* __restrict__ g1,
                                                 const float* __restrict__ bb1,
                                                 const float* __restrict__ dinv,
                                                 ushort_t* __restrict__ h16a,
                                                 unsigned char* __restrict__ h8a) {
  __shared__ float W1s[IND * HID], Wrs[IND * HID], as[16 * IND], xs[16 * IND];
  __shared__ float Tn[16][HID];
  __shared__ float stats[16][2];
  int tid = threadIdx.x;
  for (int i = tid; i < IND * HID; i += 128) { W1s[i] = W1[i]; Wrs[i] = Wr[i]; }
  long node0 = (long)blockIdx.x * 16;                 // grid = N/16 exact
  for (int i = tid; i < 16 * IND; i += 128) {
    as[i] = aggx[node0 * IND + i];
    xs[i] = x[node0 * IND + i];
  }
  float bj = b1[tid] + rb[tid];
  __syncthreads();
  for (int n = 0; n < 16; ++n) {
    float a = bj;
#pragma unroll
    for (int k = 0; k < IND; ++k) {
      a = fmaf(as[n * IND + k], W1s[k * HID + tid], a);
      a = fmaf(xs[n * IND + k], Wrs[k * HID + tid], a);
    }
    Tn[n][tid] = a;
  }
  __syncthreads();
  {
    int n = tid >> 3, sub = tid & 7;    // 8 threads per node
    float s = 0.f, q = 0.f;
#pragma unroll
    for (int k = sub; k < HID; k += 8) { float v2 = Tn[n][k]; s += v2; q += v2 * v2; }
    s += __shfl_xor(s, 1); q += __shfl_xor(q, 1);
    s += __shfl_xor(s, 2); q += __shfl_xor(q, 2);
    s += __shfl_xor(s, 4); q += __shfl_xor(q, 4);
    if (sub == 0) {
      float mu = s * (1.f / 128.f);
      float var = q * (1.f / 128.f) - mu * mu;
      stats[n][0] = mu;
      stats[n][1] = rsqrtf(var + 1e-5f);
    }
  }
  __syncthreads();
  float gj = g1[tid], bbj = bb1[tid];
  for (int n = 0; n < 16; ++n) {
    float mu = stats[n][0], rs = stats[n][1];
    float y = fmaxf(fmaf((Tn[n][tid] - mu) * rs, gj, bbj), 0.f);
    float yd = y * dinv[node0 + n];
    h16a[(node0 + n) * HID + tid] = f2bf(yd);
    h8a[(node0 + n) * HID + tid] = fp8enc1(yd);
  }
}

// ---------------- layer 2: fp8 gather + MFMA GEMM + LN + ReLU ----------------

constexpr int XSTR = 136;   // bf16 stride (pad kills stride-128 bank aliasing)
constexpr int CSTR = 132;   // fp32 C stride

__global__ __launch_bounds__(256) void k_layer2(const unsigned char* __restrict__ h8a,
                                                const ushort_t* __restrict__ h16a,
                                                const float* __restrict__ dinv,
                                                const int* __restrict__ rowptr,
                                                const int* __restrict__ colsrc,
                                                const ushort_t* __restrict__ wpack,
                                                const float* __restrict__ bias,
                                                const float* __restrict__ g2,
                                                const float* __restrict__ bb2,
                                                unsigned char* __restrict__ h8b) {
  __shared__ ushort_t XsB[16 * XSTR];   // 4.25 KB bf16 gathered X
  __shared__ float Cs[16 * CSTR];       // 8.25 KB fp32 GEMM out
  const int tid = threadIdx.x;
  const long node0 = (long)blockIdx.x * 16;           // grid = N/16 exact
  const int lane = tid & 63, w = tid >> 6;
  const int grp = lane >> 4, l16 = lane & 15, c = l16 * 8;
  // ---- phase 1: each wave gathers 4 rows (fp8, 8B/lane), bf16 into XsB ----
  for (int r = 0; r < 4; ++r) {
    const long i = node0 + w * 4 + r;
    const float di = dinv[i];
    float a0 = 0, a1 = 0, a2 = 0, a3 = 0, a4 = 0, a5 = 0, a6 = 0, a7 = 0;
    if (grp == 0) {     // self term (row already carries dinv[i])
      uint2 u = *(const uint2*)(h8a + i * HID + c);
      FP8DEC8(u, a0, a1, a2, a3, a4, a5, a6, a7);
    }
    const int e0 = rowptr[i], e1 = rowptr[i + 1];
#pragma unroll 2
    for (int e = e0; e < e1; e += 4) {
      int idx = e + grp;
      bool valid = idx < e1;
      int s = colsrc[valid ? idx : e];
      uint2 u = *(const uint2*)(h8a + (long)s * HID + c);
      if (valid) {
        float b0, b1, b2, b3, b4, b5, b6, b7;
        FP8DEC8(u, b0, b1, b2, b3, b4, b5, b6, b7);
        a0 += b0; a1 += b1; a2 += b2; a3 += b3;
        a4 += b4; a5 += b5; a6 += b6; a7 += b7;
      }
    }
    a0 += __shfl_xor(a0, 16); a0 += __shfl_xor(a0, 32);
    a1 += __shfl_xor(a1, 16); a1 += __shfl_xor(a1, 32);
    a2 += __shfl_xor(a2, 16); a2 += __shfl_xor(a2, 32);
    a3 += __shfl_xor(a3, 16); a3 += __shfl_xor(a3, 32);
    a4 += __shfl_xor(a4, 16); a4 += __shfl_xor(a4, 32);
    a5 += __shfl_xor(a5, 16); a5 += __shfl_xor(a5, 32);
    a6 += __shfl_xor(a6, 16); a6 += __shfl_xor(a6, 32);
    a7 += __shfl_xor(a7, 16); a7 += __shfl_xor(a7, 32);
    if (grp == 0) {
      uint_t p0 = (uint_t)f2bf(a0 * di) | ((uint_t)f2bf(a1 * di) << 16);
      uint_t p1 = (uint_t)f2bf(a2 * di) | ((uint_t)f2bf(a3 * di) << 16);
      uint_t p2 = (uint_t)f2bf(a4 * di) | ((uint_t)f2bf(a5 * di) << 16);
      uint_t p3 = (uint_t)f2bf(a6 * di) | ((uint_t)f2bf(a7 * di) << 16);
      *(uint4*)&XsB[(w * 4 + r) * XSTR + c] = make_uint4(p0, p1, p2, p3);
    }
  }
  __syncthreads();
  // ---- phase 2: MFMA. Wave w covers n-tiles {2w, 2w+1}. ----
  {
    const int arow = lane & 15, aq = lane >> 4;
    f32x4 acc0 = {0.f, 0.f, 0.f, 0.f}, acc1 = {0.f, 0.f, 0.f, 0.f};
    const int t0 = w * 2, t1 = w * 2 + 1;
#pragma unroll
    for (int kt = 0; kt < 4; ++kt) {
      bf16x8 af = *(const bf16x8*)&XsB[arow * XSTR + kt * 32 + aq * 8];
      bf16x8 b0 = *(const bf16x8*)&wpack[(t0 * 4 + kt) * 512 + lane * 8];
      bf16x8 b1 = *(const bf16x8*)&wpack[(t1 * 4 + kt) * 512 + lane * 8];
      acc0 = __builtin_amdgcn_mfma_f32_16x16x32_bf16(af, b0, acc0, 0, 0, 0);
      acc1 = __builtin_amdgcn_mfma_f32_16x16x32_bf16(af, b1, acc1, 0, 0, 0);
    }
#pragma unroll
    for (int r = 0; r < 4; ++r) {
      Cs[(aq * 4 + r) * CSTR + t0 * 16 + arow] = acc0[r];
      Cs[(aq * 4 + r) * CSTR + t1 * 16 + arow] = acc1[r];
    }
  }
  __syncthreads();
  // ---- phase 3: bias + residual(bf16 h16a) + LN + ReLU + fp8 store ----
  const int nidx = tid >> 5;          // 8 nodes in flight
  const int col = (tid & 31) * 4;     // 32 threads cover 128 cols
  float4 bz = *(const float4*)&bias[col];
  float4 gz = *(const float4*)&g2[col];
  float4 bbz = *(const float4*)&bb2[col];
#pragma unroll
  for (int m = 0; m < 2; ++m) {
    int nl = nidx + m * 8;
    long nm = node0 + nl;
    float di = dinv[nm];
    float rdi = 1.0f / di;
    uint2 ur = *(const uint2*)&h16a[nm * HID + col];
    float4 o = *(const float4*)&Cs[nl * CSTR + col];
    o.x += bz.x + bflo(ur.x) * rdi; o.y += bz.y + bfhi(ur.x) * rdi;
    o.z += bz.z + bflo(ur.y) * rdi; o.w += bz.w + bfhi(ur.y) * rdi;
    float s = o.x + o.y + o.z + o.w;
    float q = o.x * o.x + o.y * o.y + o.z * o.z + o.w * o.w;
#pragma unroll
    for (int off = 1; off <= 16; off <<= 1) {   // 32-lane group = one row
      s += __shfl_xor(s, off);
      q += __shfl_xor(q, off);
    }
    float mu = s * (1.f / 128.f);
    float var = q * (1.f / 128.f) - mu * mu;
    float rs = rsqrtf(var + 1e-5f);
    float y0 = fmaxf(fmaf((o.x - mu) * rs, gz.x, bbz.x), 0.f);
    float y1 = fmaxf(fmaf((o.y - mu) * rs, gz.y, bbz.y), 0.f);
    float y2 = fmaxf(fmaf((o.z - mu) * rs, gz.z, bbz.z), 0.f);
    float y3 = fmaxf(fmaf((o.w - mu) * rs, gz.w, bbz.w), 0.f);
    uint_t p = fp8pk2<false>(y0 * di, y1 * di, 0u);
    p = fp8pk2<true>(y2 * di, y3 * di, p);
    *(uint_t*)&h8b[nm * HID + col] = p;
  }
}

// ---------------- layer 3: per-bucket dense pool GEMM (NO random rows) ----------------

// partial[j] = C_j @ R_j per 128-src bucket (plain stores; reduce kernel sums).
constexpr int RSTR = 136;   // bf16 row stride for R
constexpr int CP   = 132;   // fp32 row stride for C

__global__ __launch_bounds__(256) void k_pool3m(const unsigned char* __restrict__ h8b,
                                                const int* __restrict__ bexcl2,
                                                const int* __restrict__ ebuf2,
                                                const int* __restrict__ batch,
                                                const float* __restrict__ dinv,
                                                float* __restrict__ partial) {
  __shared__ float Cm[B * CP];          // 33.8 KB
  __shared__ ushort_t R[128 * RSTR];    // 34.8 KB
  const int j = blockIdx.x, tid = threadIdx.x;
  const long nbase = (long)j * 128;
  const int validRows = min(128, N - (int)nbase);
  for (int i = tid; i < B * CP; i += 256) Cm[i] = 0.f;
  for (int i = tid; i < 128 * (HID / 8); i += 256) {
    int s = i >> 4;
    int ch = (i & 15) * 8;
    uint4 pk = make_uint4(0u, 0u, 0u, 0u);
    if (s < validRows) {
      uint2 u = *(const uint2*)(h8b + (nbase + s) * HID + ch);
      float b0, b1, b2, b3, b4, b5, b6, b7;
      FP8DEC8(u, b0, b1, b2, b3, b4, b5, b6, b7);
      pk.x = (uint_t)f2bf(b0) | ((uint_t)f2bf(b1) << 16);
      pk.y = (uint_t)f2bf(b2) | ((uint_t)f2bf(b3) << 16);
      pk.z = (uint_t)f2bf(b4) | ((uint_t)f2bf(b5) << 16);
      pk.w = (uint_t)f2bf(b6) | ((uint_t)f2bf(b7) << 16);
    }
    *(uint4*)&R[s * RSTR + ch] = pk;
  }
  __syncthreads();
  // edge-parallel C build (dinv/batch lookups deferred here; L2-resident tables)
  const int e0 = bexcl2[j], e1 = bexcl2[j + 1];
  for (int e = e0 + tid; e < e1; e += 256) {
    int p = ebuf2[e];
    int s = (p >> 17) & 127;
    int d = p & 0x1FFFF;
    atomicAdd(&Cm[batch[d] * CP + s], dinv[d]);
  }
  for (int n = tid; n < validRows; n += 256) {
    long node = nbase + n;
    atomicAdd(&Cm[batch[node] * CP + n], dinv[node]);   // self term
  }
  __syncthreads();
  // MFMA: M=64 (g), N=128 (ch), K=128 (s)
  const int lane = tid & 63, wid = tid >> 6;
  const int m16 = lane & 15, quad = lane >> 4;
  f32x4 acc[4][2];
#pragma unroll
  for (int mt = 0; mt < 4; ++mt)
#pragma unroll
    for (int ntl = 0; ntl < 2; ++ntl) acc[mt][ntl] = (f32x4){0.f, 0.f, 0.f, 0.f};
#pragma unroll
  for (int kt = 0; kt < 4; ++kt) {
    union { ushort_t u[8]; bf16x8 v; } bf[2];
#pragma unroll
    for (int ntl = 0; ntl < 2; ++ntl) {
      int nt = wid * 2 + ntl;
#pragma unroll
      for (int jj = 0; jj < 8; ++jj)
        bf[ntl].u[jj] = R[(kt * 32 + quad * 8 + jj) * RSTR + nt * 16 + m16];
    }
#pragma unroll
    for (int mt = 0; mt < 4; ++mt) {
      float4 c0 = *(const float4*)&Cm[(mt * 16 + m16) * CP + kt * 32 + quad * 8];
      float4 c1 = *(const float4*)&Cm[(mt * 16 + m16) * CP + kt * 32 + quad * 8 + 4];
      union { ushort_t u[8]; bf16x8 v; } af;
      af.u[0] = f2bf(c0.x); af.u[1] = f2bf(c0.y);
      af.u[2] = f2bf(c0.z); af.u[3] = f2bf(c0.w);
      af.u[4] = f2bf(c1.x); af.u[5] = f2bf(c1.y);
      af.u[6] = f2bf(c1.z); af.u[7] = f2bf(c1.w);
      acc[mt][0] = __builtin_amdgcn_mfma_f32_16x16x32_bf16(af.v, bf[0].v, acc[mt][0], 0, 0, 0);
      acc[mt][1] = __builtin_amdgcn_mfma_f32_16x16x32_bf16(af.v, bf[1].v, acc[mt][1], 0, 0, 0);
    }
  }
  // D: col = lane&15 (ch), row = quad*4 + r (g). Plain stores to partial slab.
  float* slab = partial + (long)j * (B * HID);
#pragma unroll
  for (int mt = 0; mt < 4; ++mt)
#pragma unroll
    for (int ntl = 0; ntl < 2; ++ntl)
#pragma unroll
      for (int r = 0; r < 4; ++r) {
        int g = mt * 16 + quad * 4 + r;
        int ch = (wid * 2 + ntl) * 16 + m16;
        slab[g * HID + ch] = acc[mt][ntl][r];
      }
}

// pooled[o] = sum_j partial[j][o]; 256 blocks x 32 outputs, 8-way j-parallel.
__global__ __launch_bounds__(256) void k_pool_reduce(const float* __restrict__ partial,
                                                     float* __restrict__ pooled) {
  __shared__ float s[256];
  const int ol = threadIdx.x & 31, jl = threadIdx.x >> 5;
  const int o = blockIdx.x * 32 + ol;
  float acc = 0.f;
  for (int j = jl; j < NBUK; j += 8)
    acc += partial[(long)j * (B * HID) + o];
  s[threadIdx.x] = acc;
  __syncthreads();
  if (threadIdx.x < 32) {
    float a = s[threadIdx.x];
#pragma unroll
    for (int k = 1; k < 8; ++k) a += s[k * 32 + threadIdx.x];
    pooled[o] = a;
  }
}

// ---------------- final GEMM ----------------

// out[g] = (pooled[g]/cnt) @ W3 + b3
__global__ __launch_bounds__(256) void k_final(const float* __restrict__ pooled,
                                               const int* __restrict__ starts,
                                               const float* __restrict__ W3,
                                               const float* __restrict__ b3,
                                               float* __restrict__ out) {
  __shared__ float p[HID];
  int g = blockIdx.x, tid = threadIdx.x;
  int len = starts[g + 1] - starts[g];
  float scale = 1.0f / fmaxf((float)len, 1.0f);
  if (tid < HID) p[tid] = pooled[g * HID + tid] * scale;
  __syncthreads();
  float a = b3[tid];
  for (int k = 0; k < HID; ++k) a = fmaf(p[k], W3[k * OUTD + tid], a);
  out[g * OUTD + tid] = a;
}

// ---------------- launch ----------------

extern "C" void kernel_launch(void* const* d_in, const int* in_sizes, int n_in,
                              void* d_out, int out_size, void* d_ws, size_t ws_size,
                              hipStream_t stream) {
  const float* x    = (const float*)d_in[0];
  const int*   eidx = (const int*)d_in[1];
  const int*   batch= (const int*)d_in[2];
  const float* W1   = (const float*)d_in[3];
  const float* b1   = (const float*)d_in[4];
  const float* W2   = (const float*)d_in[5];
  const float* b2   = (const float*)d_in[6];
  const float* W3   = (const float*)d_in[7];
  const float* b3   = (const float*)d_in[8];
  const float* resW = (const float*)d_in[9];
  const float* resb = (const float*)d_in[10];
  const float* g1   = (const float*)d_in[11];
  const float* bb1  = (const float*)d_in[12];
  const float* g2   = (const float*)d_in[13];
  const float* bb2  = (const float*)d_in[14];
  float* out = (float*)d_out;

  char* w = (char*)d_ws;
  size_t off = 0;
  auto alloc = [&](size_t bytes) {
    char* p = w + off;
    off = (off + bytes + 1023) & ~(size_t)1023;
    return p;
  };
  float* dinv   = (float*)alloc((size_t)N * 4);
  int*   rowptr = (int*)alloc((size_t)(N + 1) * 4);
  int*   colsrc = (int*)alloc((size_t)E * 4);
  int*   ebuf   = (int*)alloc((size_t)E * 4);
  int*   ebuf2  = (int*)alloc((size_t)E * 4);
  int*   hist   = (int*)alloc((size_t)GB * NBUK * 4);
  int*   hist2  = (int*)alloc((size_t)GB * NBUK * 4);
  int*   btotal = (int*)alloc((size_t)NBUK * 4);
  int*   btotal2= (int*)alloc((size_t)NBUK * 4);
  int*   bexcl  = (int*)alloc((size_t)(NBUK + 1) * 4);
  int*   bexcl2 = (int*)alloc((size_t)(NBUK + 1) * 4);
  int*   starts = (int*)alloc((size_t)(B + 1) * 4);
  float* pooled = (float*)alloc((size_t)B * HID * 4);
  float* aggx   = (float*)alloc((size_t)N * IND * 4);
  ushort_t* h16a= (ushort_t*)alloc((size_t)N * HID * 2);   // 25.6 MB
  ushort_t* xs16= (ushort_t*)alloc((size_t)N * IND * 2);   // 4.0 MB (follows h16a)
  ushort_t* wpack=(ushort_t*)alloc((size_t)HID * HID * 2);
  unsigned char* h8a = (unsigned char*)alloc((size_t)N * HID);
  unsigned char* h8b = (unsigned char*)alloc((size_t)N * HID);
  // partial pool slabs (782 x 8192 fp32 = 25.63 MB) alias the dead
  // h16a+xs16 region (29.6 MB contiguous; both dead before k_pool3m runs).
  float* partial = (float*)h16a;

  // ---- CSR builds (dst + src order) + norm + starts + xs16 + W2 pack ----
  k_seg_starts<<<(N + 255) / 256, 256, 0, stream>>>(batch, starts);
  k_packW2<<<64, 256, 0, stream>>>(W2, wpack);
  k_hist<<<GB, 256, 0, stream>>>(eidx, hist, hist2);
  k_bscan<<<NBUK, 256, 0, stream>>>(hist, btotal);
  k_bscan<<<NBUK, 256, 0, stream>>>(hist2, btotal2);
  k_bktscan<<<1, 256, 0, stream>>>(btotal, bexcl, rowptr);
  k_bktscan<<<1, 256, 0, stream>>>(btotal2, bexcl2, rowptr);
  k_scatter<<<GB, 256, 0, stream>>>(eidx, hist, bexcl, hist2, bexcl2, ebuf, ebuf2);
  k_csr<<<NBUK, 256, 0, stream>>>(ebuf, bexcl, x, rowptr, dinv, colsrc, xs16);

  // ---- layer 1: 20-dim gather, conv1 + LN1 + ReLU (bf16 + fp8 out) ----
  k_gather20b<<<N / 25, 256, 0, stream>>>(xs16, dinv, rowptr, colsrc, aggx);
  k_conv1ln<<<N / 16, 128, 0, stream>>>(aggx, x, W1, b1, resW, resb,
                                        g1, bb1, dinv, h16a, h8a);

  // ---- layer 2: fp8 gather + MFMA GEMM + LN2 + ReLU (fused), fp8 out ----
  k_layer2<<<N / 16, 256, 0, stream>>>(h8a, h16a, dinv, rowptr, colsrc,
                                       wpack, b2, g2, bb2, h8b);

  // ---- layer 3: dense per-bucket pool GEMM -> partial slabs -> reduce ----
  k_pool3m<<<NBUK, 256, 0, stream>>>(h8b, bexcl2, ebuf2, batch, dinv, partial);
  k_pool_reduce<<<(B * HID) / 32, 256, 0, stream>>>(partial, pooled);
  k_final<<<B, 256, 0, stream>>>(pooled, starts, W3, b3, out);
}

// Round 15
// 340.116 us; speedup vs baseline: 1.1859x; 1.1556x over previous
//
#include <hip/hip_runtime.h>
#include <hip/hip_bf16.h>
#include <hip/hip_fp16.h>
#include <hip/hip_fp8.h>

// GCN: N=100000 nodes, E=1600000 edges, B=64 graphs, 20 -> 128 -> 128 -> 256.
// Strategy log:
//  - gcn_conv(h,W) = (scatter_norm(h)) @ W; mean-pool commutes with W3.
//  - R1 sorted-batch seg starts; R3 two-level bucket-sort CSR.
//  - R4-R8: gathers pinned by random line traffic; fp8 payloads (R7).
//  - R9 lesson: edge-parallel scatter or bust. R11: layer2 GEMM on MFMA.
//  - R12/13: layer-3 -> dense per-bucket GEMM (C@R) + partial slabs + reduce;
//    merged dual-order edge scatter.
//  - R13 analysis: layer2 FETCH = 8 XCD x 12.8MB table = compulsory floor.
//  - R14: h16a residual buffer DELETED (residual from fp8 h8a, -51MB traffic);
//    conv1 moved to MFMA (packed [W1|resW], K=64, bf16 aggx); launch merges
//    (packs, bscans, bktscans) 16 -> 13 kernels.

typedef unsigned short ushort_t;
typedef unsigned int uint_t;
typedef __attribute__((ext_vector_type(8))) short bf16x8;
typedef __attribute__((ext_vector_type(4))) float f32x4;

constexpr int N  = 100000;
constexpr int E  = 1600000;
constexpr int B  = 64;
constexpr int IND = 20;
constexpr int HID = 128;
constexpr int OUTD = 256;

constexpr int NBUK = (N + 127) / 128;   // 782 buckets of 128 nodes
constexpr int GB   = 256;               // hist/scatter blocks
constexpr int EPB  = E / GB;            // 6250 edges per block
constexpr int BMAX = 3072;              // LDS cap per bucket (mean 2048, sd ~45)

// bf16 helpers (RNE pack, shift-unpack)
__device__ inline ushort_t f2bf(float f) {
  union { float f; uint_t u; } v; v.f = f;
  uint_t r = v.u + 0x7fffu + ((v.u >> 16) & 1u);
  return (ushort_t)(r >> 16);
}
__device__ inline float bflo(uint_t u) { return __uint_as_float(u << 16); }
__device__ inline float bfhi(uint_t u) { return __uint_as_float(u & 0xffff0000u); }

// fp8 e4m3 helpers (HW cvt on gfx950; hip_fp8.h fallback)
#if defined(__has_builtin)
#if __has_builtin(__builtin_amdgcn_cvt_f32_fp8) && __has_builtin(__builtin_amdgcn_cvt_pk_fp8_f32)
#define FP8_HW 1
#endif
#endif

template <int S>
__device__ inline float fp8dec(uint_t u) {
#ifdef FP8_HW
  return __builtin_amdgcn_cvt_f32_fp8(u, S);
#else
  __hip_fp8_storage_t b = (__hip_fp8_storage_t)((u >> (8 * S)) & 0xffu);
  __half_raw hr = __hip_cvt_fp8_to_halfraw(b, __HIP_E4M3);
  return __half2float(*(__half*)&hr);
#endif
}

template <bool W>
__device__ inline uint_t fp8pk2(float a, float b, uint_t old) {
#ifdef FP8_HW
  return __builtin_amdgcn_cvt_pk_fp8_f32(a, b, old, W);
#else
  uint_t lo = (uint_t)__hip_cvt_float_to_fp8(a, __HIP_SATFINITE, __HIP_E4M3);
  uint_t hi = (uint_t)__hip_cvt_float_to_fp8(b, __HIP_SATFINITE, __HIP_E4M3);
  uint_t pair = lo | (hi << 8);
  return W ? ((old & 0x0000ffffu) | (pair << 16)) : ((old & 0xffff0000u) | pair);
#endif
}

__device__ inline unsigned char fp8enc1(float a) {
  return (unsigned char)(fp8pk2<false>(a, a, 0u) & 0xffu);
}

// decode 8 fp8 (uint2) into a[0..7]
#define FP8DEC8(u, a0, a1, a2, a3, a4, a5, a6, a7) \
  { a0 = fp8dec<0>(u.x); a1 = fp8dec<1>(u.x); a2 = fp8dec<2>(u.x); a3 = fp8dec<3>(u.x); \
    a4 = fp8dec<0>(u.y); a5 = fp8dec<1>(u.y); a6 = fp8dec<2>(u.y); a7 = fp8dec<3>(u.y); }

// ---------------- init + segment starts ----------------

__global__ __launch_bounds__(256) void k_seg_starts(const int* __restrict__ batch,
                                                    int* __restrict__ starts) {
  int i = blockIdx.x * 256 + threadIdx.x;
  if (i >= N) return;
  int b = batch[i];
  int prev = (i == 0) ? -1 : batch[i - 1];
  for (int g = prev + 1; g <= b; ++g) starts[g] = i;  // fires only at boundaries
  if (i == N - 1)
    for (int g = b + 1; g <= B; ++g) starts[g] = N;
}

// Pack W2 into MFMA B-frag order (16384 entries) AND [W1|resW] K=64 pack
// (8192 entries). B-frag: lane&15 = n, (lane>>4)*8+j = k-within-ktile.
__global__ __launch_bounds__(256) void k_pack(const float* __restrict__ W2,
                                              const float* __restrict__ W1,
                                              const float* __restrict__ resW,
                                              ushort_t* __restrict__ wpack,
                                              ushort_t* __restrict__ w1pack) {
  int idx = blockIdx.x * 256 + threadIdx.x;   // 96 blocks = 24576
  if (idx < 16384) {
    int j = idx & 7, L = (idx >> 3) & 63, kt = (idx >> 9) & 3, t = idx >> 11;
    int k = kt * 32 + ((L >> 4) & 3) * 8 + j;
    int n = t * 16 + (L & 15);
    wpack[idx] = f2bf(W2[k * HID + n]);
  } else {
    int i2 = idx - 16384;
    int j = i2 & 7, L = (i2 >> 3) & 63, kt = (i2 >> 9) & 1, t = i2 >> 10;
    int k = kt * 32 + ((L >> 4) & 3) * 8 + j;
    int n = t * 16 + (L & 15);
    float v = 0.f;
    if (k < IND) v = W1[k * HID + n];
    else if (k >= 32 && k < 32 + IND) v = resW[(k - 32) * HID + n];
    w1pack[i2] = f2bf(v);
  }
}

// ---------------- CSR builds: bucket sorts by dst AND by src ----------------

__global__ __launch_bounds__(256) void k_hist(const int* __restrict__ eidx,
                                              int* __restrict__ histd,
                                              int* __restrict__ hists) {
  __shared__ int hd[NBUK], hs[NBUK];
  for (int i = threadIdx.x; i < NBUK; i += 256) { hd[i] = 0; hs[i] = 0; }
  __syncthreads();
  const long base = (long)blockIdx.x * EPB;
  for (int i = threadIdx.x; i < EPB; i += 256) {
    atomicAdd(&hs[eidx[base + i] >> 7], 1);
    atomicAdd(&hd[eidx[E + base + i] >> 7], 1);
  }
  __syncthreads();
  for (int i = threadIdx.x; i < NBUK; i += 256) {
    histd[(long)blockIdx.x * NBUK + i] = hd[i];
    hists[(long)blockIdx.x * NBUK + i] = hs[i];
  }
}

// Both per-bucket scans in one launch: grid = 2*NBUK.
__global__ __launch_bounds__(256) void k_bscan2x(int* __restrict__ histd,
                                                 int* __restrict__ btd,
                                                 int* __restrict__ hists,
                                                 int* __restrict__ bts) {
  __shared__ int s[256];
  const int which = (blockIdx.x >= NBUK);
  const int j = which ? blockIdx.x - NBUK : blockIdx.x;
  int* hist = which ? hists : histd;
  int* btotal = which ? bts : btd;
  const int tid = threadIdx.x;
  int v = hist[(long)tid * NBUK + j];
  s[tid] = v;
  for (int off = 1; off < 256; off <<= 1) {
    __syncthreads();
    int x = (tid >= off) ? s[tid - off] : 0;
    __syncthreads();
    s[tid] += x;
  }
  hist[(long)tid * NBUK + j] = s[tid] - v;   // exclusive within bucket
  if (tid == 255) btotal[j] = s[255];
}

// Both bucket-total scans in one launch: grid = 2.
__global__ __launch_bounds__(256) void k_bktscan2x(const int* __restrict__ btd,
                                                   int* __restrict__ bexcl,
                                                   const int* __restrict__ bts,
                                                   int* __restrict__ bexcl2,
                                                   int* __restrict__ rowptr) {
  __shared__ int s[256];
  const int* bt = blockIdx.x ? bts : btd;
  int* bx = blockIdx.x ? bexcl2 : bexcl;
  int tid = threadIdx.x;
  int base = tid * 4;
  int v0 = (base + 0 < NBUK) ? bt[base + 0] : 0;
  int v1 = (base + 1 < NBUK) ? bt[base + 1] : 0;
  int v2 = (base + 2 < NBUK) ? bt[base + 2] : 0;
  int v3 = (base + 3 < NBUK) ? bt[base + 3] : 0;
  int p0 = v0, p1 = p0 + v1, p2 = p1 + v2, p3 = p2 + v3;
  s[tid] = p3;
  for (int off = 1; off < 256; off <<= 1) {
    __syncthreads();
    int x = (tid >= off) ? s[tid - off] : 0;
    __syncthreads();
    s[tid] += x;
  }
  int excl = s[tid] - p3;
  if (base + 0 < NBUK) bx[base + 1] = excl + p0;
  if (base + 1 < NBUK) bx[base + 2] = excl + p1;
  if (base + 2 < NBUK) bx[base + 3] = excl + p2;
  if (base + 3 < NBUK) bx[base + 4] = excl + p3;
  if (tid == 0) { bx[0] = 0; if (blockIdx.x == 0) rowptr[N] = E; }
}

// Merged scatter: ONE edge pass writes BOTH orderings.
// ebuf (dst-order):  src(20b) | dstlow(7b)<<20
// ebuf2 (src-order): srclow(7b)<<17 | dst(17b)
__global__ __launch_bounds__(256) void k_scatter(const int* __restrict__ eidx,
                                                 const int* __restrict__ histd,
                                                 const int* __restrict__ bexcl,
                                                 const int* __restrict__ hists,
                                                 const int* __restrict__ bexcl2,
                                                 int* __restrict__ ebuf,
                                                 int* __restrict__ ebuf2) {
  __shared__ int hd[NBUK], hs[NBUK];
  for (int i = threadIdx.x; i < NBUK; i += 256) {
    hd[i] = bexcl[i] + histd[(long)blockIdx.x * NBUK + i];
    hs[i] = bexcl2[i] + hists[(long)blockIdx.x * NBUK + i];
  }
  __syncthreads();
  const long base = (long)blockIdx.x * EPB;
  for (int i = threadIdx.x; i < EPB; i += 256) {
    int s = eidx[base + i];
    int d = eidx[E + base + i];
    int pos = atomicAdd(&hd[d >> 7], 1);
    ebuf[pos] = s | ((d & 127) << 20);
    int pos2 = atomicAdd(&hs[s >> 7], 1);
    ebuf2[pos2] = ((s & 127) << 17) | d;
  }
}

// One block per dst-bucket: LDS counting sort -> rowptr/dinv/colsrc + xs16.
__global__ __launch_bounds__(256) void k_csr(const int* __restrict__ ebuf,
                                             const int* __restrict__ bexcl,
                                             const float* __restrict__ x,
                                             int* __restrict__ rowptr,
                                             float* __restrict__ dinv,
                                             int* __restrict__ colsrc,
                                             ushort_t* __restrict__ xs16) {
  __shared__ int deg[128], s[128], cur[128];
  __shared__ float dv[128];
  __shared__ int lout[BMAX];
  const int j = blockIdx.x, tid = threadIdx.x;
  const int e0 = bexcl[j], e1 = bexcl[j + 1];
  const int cnt = e1 - e0;
  if (tid < 128) deg[tid] = 0;
  __syncthreads();
  for (int i = tid; i < cnt; i += 256)
    atomicAdd(&deg[(ebuf[e0 + i] >> 20) & 127], 1);
  __syncthreads();
  int v = (tid < 128) ? deg[tid] : 0;
  if (tid < 128) s[tid] = v;
  for (int off = 1; off < 128; off <<= 1) {
    __syncthreads();
    int x2 = (tid < 128 && tid >= off) ? s[tid - off] : 0;
    __syncthreads();
    if (tid < 128) s[tid] += x2;
  }
  __syncthreads();
  if (tid < 128) {
    int ex = s[tid] - v;
    cur[tid] = ex;
    float d = rsqrtf((float)(1 + v));   // deg includes self-loop
    dv[tid] = d;
    int node = j * 128 + tid;
    if (node < N) {
      rowptr[node] = e0 + ex;
      dinv[node] = d;
    }
  }
  __syncthreads();
  if (cnt <= BMAX) {
    for (int i = tid; i < cnt; i += 256) {
      int p = ebuf[e0 + i];
      int pos = atomicAdd(&cur[(p >> 20) & 127], 1);
      lout[pos] = p & 0xFFFFF;
    }
    __syncthreads();
    for (int i = tid; i < cnt; i += 256) colsrc[e0 + i] = lout[i];
  } else {  // safety fallback
    for (int i = tid; i < cnt; i += 256) {
      int p = ebuf[e0 + i];
      int pos = atomicAdd(&cur[(p >> 20) & 127], 1);
      colsrc[e0 + pos] = p & 0xFFFFF;
    }
  }
  for (int idx = tid; idx < 128 * IND; idx += 256) {
    int n = idx / IND;
    long node = (long)j * 128 + n;
    if (node < N)
      xs16[node * IND + idx % IND] = f2bf(x[node * IND + idx % IND] * dv[n]);
  }
}

// ---------------- layer 1 ----------------

// 20-dim gather over bf16 x*dinv rows: 10 threads/node, 2 channels each.
// Output aggx16 = bf16(dinv * (self + sum)).
__global__ __launch_bounds__(256) void k_gather20b(const ushort_t* __restrict__ xs16,
                                                   const float* __restrict__ dinv,
                                                   const int* __restrict__ rowptr,
                                                   const int* __restrict__ colsrc,
                                                   ushort_t* __restrict__ aggx16) {
  int t = threadIdx.x;
  if (t >= 250) return;
  int n = t / 10, cc = (t % 10) * 2;
  long i = (long)blockIdx.x * 25 + n;               // grid = N/25 exact
  float di = dinv[i];
  uint_t u = *(const uint_t*)(xs16 + i * IND + cc);
  float a0 = bflo(u), a1 = bfhi(u);
  int e0 = rowptr[i], e1 = rowptr[i + 1];
#pragma unroll 4
  for (int e = e0; e < e1; ++e) {
    int s = colsrc[e];
    uint_t v = *(const uint_t*)(xs16 + (long)s * IND + cc);
    a0 += bflo(v); a1 += bfhi(v);
  }
  uint_t p0 = f2bf(a0 * di), p1 = f2bf(a1 * di);
  *(uint_t*)&aggx16[i * IND + cc] = p0 | (p1 << 16);
}

// conv1 on MFMA: h1 = relu(LN1([aggx|x] @ [W1;resW] + b1 + resb)).
// A = 16 nodes x K=64 bf16 (k<20: aggx16, 32<=k<52: bf16(x), else 0).
// Output fp8(h1*dinv) only (residual reconstructed from it in layer2).
constexpr int ASTR = 72;    // bf16 A stride
constexpr int CSTR = 132;   // fp32 C stride

__global__ __launch_bounds__(256) void k_conv1m(const ushort_t* __restrict__ aggx16,
                                                const float* __restrict__ x,
                                                const ushort_t* __restrict__ w1pack,
                                                const float* __restrict__ b1,
                                                const float* __restrict__ resb,
                                                const float* __restrict__ g1,
                                                const float* __restrict__ bb1,
                                                const float* __restrict__ dinv,
                                                unsigned char* __restrict__ h8a) {
  __shared__ ushort_t A[16 * ASTR];   // 2.25 KB
  __shared__ float Cs[16 * CSTR];     // 8.25 KB
  const int tid = threadIdx.x;
  const long node0 = (long)blockIdx.x * 16;           // grid = N/16 exact
  for (int idx = tid; idx < 16 * 64; idx += 256) {
    int n = idx >> 6, k = idx & 63;
    ushort_t v = 0;
    if (k < IND) v = aggx16[(node0 + n) * IND + k];
    else if (k >= 32 && k < 32 + IND) v = f2bf(x[(node0 + n) * IND + (k - 32)]);
    A[n * ASTR + k] = v;
  }
  __syncthreads();
  const int lane = tid & 63, w = tid >> 6;
  {
    const int arow = lane & 15, aq = lane >> 4;
    f32x4 acc0 = {0.f, 0.f, 0.f, 0.f}, acc1 = {0.f, 0.f, 0.f, 0.f};
    const int t0 = w * 2, t1 = t0 + 1;
#pragma unroll
    for (int kt = 0; kt < 2; ++kt) {
      bf16x8 af = *(const bf16x8*)&A[arow * ASTR + kt * 32 + aq * 8];
      bf16x8 b0 = *(const bf16x8*)&w1pack[(t0 * 2 + kt) * 512 + lane * 8];
      bf16x8 b1f = *(const bf16x8*)&w1pack[(t1 * 2 + kt) * 512 + lane * 8];
      acc0 = __builtin_amdgcn_mfma_f32_16x16x32_bf16(af, b0, acc0, 0, 0, 0);
      acc1 = __builtin_amdgcn_mfma_f32_16x16x32_bf16(af, b1f, acc1, 0, 0, 0);
    }
#pragma unroll
    for (int r = 0; r < 4; ++r) {
      Cs[(aq * 4 + r) * CSTR + t0 * 16 + arow] = acc0[r];
      Cs[(aq * 4 + r) * CSTR + t1 * 16 + arow] = acc1[r];
    }
  }
  __syncthreads();
  const int nidx = tid >> 5, col = (tid & 31) * 4;
  float4 bz = *(const float4*)&b1[col];
  float4 rz = *(const float4*)&resb[col];
  bz.x += rz.x; bz.y += rz.y; bz.z += rz.z; bz.w += rz.w;
  float4 gz = *(const float4*)&g1[col];
  float4 bbz = *(const float4*)&bb1[col];
#pragma unroll
  for (int m = 0; m < 2; ++m) {
    int nl = nidx + m * 8;
    long nm = node0 + nl;
    float4 o = *(const float4*)&Cs[nl * CSTR + col];
    o.x += bz.x; o.y += bz.y; o.z += bz.z; o.w += bz.w;
    float s = o.x + o.y + o.z + o.w;
    float q = o.x * o.x + o.y * o.y + o.z * o.z + o.w * o.w;
#pragma unroll
    for (int off = 1; off <= 16; off <<= 1) {
      s += __shfl_xor(s, off);
      q += __shfl_xor(q, off);
    }
    float mu = s * (1.f / 128.f);
    float var = q * (1.f / 128.f) - mu * mu;
    float rs = rsqrtf(var + 1e-5f);
    float y0 = fmaxf(fmaf((o.x - mu) * rs, gz.x, bbz.x), 0.f);
    float y1 = fmaxf(fmaf((o.y - mu) * rs, gz.y, bbz.y), 0.f);
    float y2 = fmaxf(fmaf((o.z - mu) * rs, gz.z, bbz.z), 0.f);
    float y3 = fmaxf(fmaf((o.w - mu) * rs, gz.w, bbz.w), 0.f);
    float di = dinv[nm];
    uint_t p = fp8pk2<false>(y0 * di, y1 * di, 0u);
    p = fp8pk2<true>(y2 * di, y3 * di, p);
    *(uint_t*)&h8a[nm * HID + col] = p;
  }
}

// ---------------- layer 2: fp8 gather + MFMA GEMM + LN + ReLU ----------------

constexpr int XSTR = 136;   // bf16 stride

__global__ __launch_bounds__(256) void k_layer2(const unsigned char* __restrict__ h8a,
                                                const float* __restrict__ dinv,
                                                const int* __restrict__ rowptr,
                                                const int* __restrict__ colsrc,
                                                const ushort_t* __restrict__ wpack,
                                                const float* __restrict__ bias,
                                                const float* __restrict__ g2,
                                                const float* __restrict__ bb2,
                                                unsigned char* __restrict__ h8b) {
  __shared__ ushort_t XsB[16 * XSTR];   // 4.25 KB bf16 gathered X
  __shared__ float Cs[16 * CSTR];       // 8.25 KB fp32 GEMM out
  const int tid = threadIdx.x;
  const long node0 = (long)blockIdx.x * 16;           // grid = N/16 exact
  const int lane = tid & 63, w = tid >> 6;
  const int grp = lane >> 4, l16 = lane & 15, c = l16 * 8;
  // ---- phase 1: each wave gathers 4 rows (fp8, 8B/lane), bf16 into XsB ----
  for (int r = 0; r < 4; ++r) {
    const long i = node0 + w * 4 + r;
    const float di = dinv[i];
    float a0 = 0, a1 = 0, a2 = 0, a3 = 0, a4 = 0, a5 = 0, a6 = 0, a7 = 0;
    if (grp == 0) {     // self term (row already carries dinv[i])
      uint2 u = *(const uint2*)(h8a + i * HID + c);
      FP8DEC8(u, a0, a1, a2, a3, a4, a5, a6, a7);
    }
    const int e0 = rowptr[i], e1 = rowptr[i + 1];
#pragma unroll 2
    for (int e = e0; e < e1; e += 4) {
      int idx = e + grp;
      bool valid = idx < e1;
      int s = colsrc[valid ? idx : e];
      uint2 u = *(const uint2*)(h8a + (long)s * HID + c);
      if (valid) {
        float b0, b1, b2, b3, b4, b5, b6, b7;
        FP8DEC8(u, b0, b1, b2, b3, b4, b5, b6, b7);
        a0 += b0; a1 += b1; a2 += b2; a3 += b3;
        a4 += b4; a5 += b5; a6 += b6; a7 += b7;
      }
    }
    a0 += __shfl_xor(a0, 16); a0 += __shfl_xor(a0, 32);
    a1 += __shfl_xor(a1, 16); a1 += __shfl_xor(a1, 32);
    a2 += __shfl_xor(a2, 16); a2 += __shfl_xor(a2, 32);
    a3 += __shfl_xor(a3, 16); a3 += __shfl_xor(a3, 32);
    a4 += __shfl_xor(a4, 16); a4 += __shfl_xor(a4, 32);
    a5 += __shfl_xor(a5, 16); a5 += __shfl_xor(a5, 32);
    a6 += __shfl_xor(a6, 16); a6 += __shfl_xor(a6, 32);
    a7 += __shfl_xor(a7, 16); a7 += __shfl_xor(a7, 32);
    if (grp == 0) {
      uint_t p0 = (uint_t)f2bf(a0 * di) | ((uint_t)f2bf(a1 * di) << 16);
      uint_t p1 = (uint_t)f2bf(a2 * di) | ((uint_t)f2bf(a3 * di) << 16);
      uint_t p2 = (uint_t)f2bf(a4 * di) | ((uint_t)f2bf(a5 * di) << 16);
      uint_t p3 = (uint_t)f2bf(a6 * di) | ((uint_t)f2bf(a7 * di) << 16);
      *(uint4*)&XsB[(w * 4 + r) * XSTR + c] = make_uint4(p0, p1, p2, p3);
    }
  }
  __syncthreads();
  // ---- phase 2: MFMA. Wave w covers n-tiles {2w, 2w+1}. ----
  {
    const int arow = lane & 15, aq = lane >> 4;
    f32x4 acc0 = {0.f, 0.f, 0.f, 0.f}, acc1 = {0.f, 0.f, 0.f, 0.f};
    const int t0 = w * 2, t1 = w * 2 + 1;
#pragma unroll
    for (int kt = 0; kt < 4; ++kt) {
      bf16x8 af = *(const bf16x8*)&XsB[arow * XSTR + kt * 32 + aq * 8];
      bf16x8 b0 = *(const bf16x8*)&wpack[(t0 * 4 + kt) * 512 + lane * 8];
      bf16x8 b1 = *(const bf16x8*)&wpack[(t1 * 4 + kt) * 512 + lane * 8];
      acc0 = __builtin_amdgcn_mfma_f32_16x16x32_bf16(af, b0, acc0, 0, 0, 0);
      acc1 = __builtin_amdgcn_mfma_f32_16x16x32_bf16(af, b1, acc1, 0, 0, 0);
    }
#pragma unroll
    for (int r = 0; r < 4; ++r) {
      Cs[(aq * 4 + r) * CSTR + t0 * 16 + arow] = acc0[r];
      Cs[(aq * 4 + r) * CSTR + t1 * 16 + arow] = acc1[r];
    }
  }
  __syncthreads();
  // ---- phase 3: bias + residual(fp8 h8a) + LN + ReLU + fp8 store ----
  const int nidx = tid >> 5;
  const int col = (tid & 31) * 4;
  float4 bz = *(const float4*)&bias[col];
  float4 gz = *(const float4*)&g2[col];
  float4 bbz = *(const float4*)&bb2[col];
#pragma unroll
  for (int m = 0; m < 2; ++m) {
    int nl = nidx + m * 8;
    long nm = node0 + nl;
    float di = dinv[nm];
    float rdi = 1.0f / di;
    uint_t ur = *(const uint_t*)&h8a[nm * HID + col];   // fp8 residual (L2-hot)
    float4 o = *(const float4*)&Cs[nl * CSTR + col];
    o.x += bz.x + fp8dec<0>(ur) * rdi;
    o.y += bz.y + fp8dec<1>(ur) * rdi;
    o.z += bz.z + fp8dec<2>(ur) * rdi;
    o.w += bz.w + fp8dec<3>(ur) * rdi;
    float s = o.x + o.y + o.z + o.w;
    float q = o.x * o.x + o.y * o.y + o.z * o.z + o.w * o.w;
#pragma unroll
    for (int off = 1; off <= 16; off <<= 1) {
      s += __shfl_xor(s, off);
      q += __shfl_xor(q, off);
    }
    float mu = s * (1.f / 128.f);
    float var = q * (1.f / 128.f) - mu * mu;
    float rs = rsqrtf(var + 1e-5f);
    float y0 = fmaxf(fmaf((o.x - mu) * rs, gz.x, bbz.x), 0.f);
    float y1 = fmaxf(fmaf((o.y - mu) * rs, gz.y, bbz.y), 0.f);
    float y2 = fmaxf(fmaf((o.z - mu) * rs, gz.z, bbz.z), 0.f);
    float y3 = fmaxf(fmaf((o.w - mu) * rs, gz.w, bbz.w), 0.f);
    uint_t p = fp8pk2<false>(y0 * di, y1 * di, 0u);
    p = fp8pk2<true>(y2 * di, y3 * di, p);
    *(uint_t*)&h8b[nm * HID + col] = p;
  }
}

// ---------------- layer 3: per-bucket dense pool GEMM ----------------

constexpr int RSTR = 136;   // bf16 row stride for R
constexpr int CP   = 132;   // fp32 row stride for C

__global__ __launch_bounds__(256) void k_pool3m(const unsigned char* __restrict__ h8b,
                                                const int* __restrict__ bexcl2,
                                                const int* __restrict__ ebuf2,
                                                const int* __restrict__ batch,
                                                const float* __restrict__ dinv,
                                                float* __restrict__ partial) {
  __shared__ float Cm[B * CP];          // 33.8 KB
  __shared__ ushort_t R[128 * RSTR];    // 34.8 KB
  const int j = blockIdx.x, tid = threadIdx.x;
  const long nbase = (long)j * 128;
  const int validRows = min(128, N - (int)nbase);
  for (int i = tid; i < B * CP; i += 256) Cm[i] = 0.f;
  for (int i = tid; i < 128 * (HID / 8); i += 256) {
    int s = i >> 4;
    int ch = (i & 15) * 8;
    uint4 pk = make_uint4(0u, 0u, 0u, 0u);
    if (s < validRows) {
      uint2 u = *(const uint2*)(h8b + (nbase + s) * HID + ch);
      float b0, b1, b2, b3, b4, b5, b6, b7;
      FP8DEC8(u, b0, b1, b2, b3, b4, b5, b6, b7);
      pk.x = (uint_t)f2bf(b0) | ((uint_t)f2bf(b1) << 16);
      pk.y = (uint_t)f2bf(b2) | ((uint_t)f2bf(b3) << 16);
      pk.z = (uint_t)f2bf(b4) | ((uint_t)f2bf(b5) << 16);
      pk.w = (uint_t)f2bf(b6) | ((uint_t)f2bf(b7) << 16);
    }
    *(uint4*)&R[s * RSTR + ch] = pk;
  }
  __syncthreads();
  const int e0 = bexcl2[j], e1 = bexcl2[j + 1];
  for (int e = e0 + tid; e < e1; e += 256) {
    int p = ebuf2[e];
    int s = (p >> 17) & 127;
    int d = p & 0x1FFFF;
    atomicAdd(&Cm[batch[d] * CP + s], dinv[d]);
  }
  for (int n = tid; n < validRows; n += 256) {
    long node = nbase + n;
    atomicAdd(&Cm[batch[node] * CP + n], dinv[node]);   // self term
  }
  __syncthreads();
  const int lane = tid & 63, wid = tid >> 6;
  const int m16 = lane & 15, quad = lane >> 4;
  f32x4 acc[4][2];
#pragma unroll
  for (int mt = 0; mt < 4; ++mt)
#pragma unroll
    for (int ntl = 0; ntl < 2; ++ntl) acc[mt][ntl] = (f32x4){0.f, 0.f, 0.f, 0.f};
#pragma unroll
  for (int kt = 0; kt < 4; ++kt) {
    union { ushort_t u[8]; bf16x8 v; } bf[2];
#pragma unroll
    for (int ntl = 0; ntl < 2; ++ntl) {
      int nt = wid * 2 + ntl;
#pragma unroll
      for (int jj = 0; jj < 8; ++jj)
        bf[ntl].u[jj] = R[(kt * 32 + quad * 8 + jj) * RSTR + nt * 16 + m16];
    }
#pragma unroll
    for (int mt = 0; mt < 4; ++mt) {
      float4 c0 = *(const float4*)&Cm[(mt * 16 + m16) * CP + kt * 32 + quad * 8];
      float4 c1 = *(const float4*)&Cm[(mt * 16 + m16) * CP + kt * 32 + quad * 8 + 4];
      union { ushort_t u[8]; bf16x8 v; } af;
      af.u[0] = f2bf(c0.x); af.u[1] = f2bf(c0.y);
      af.u[2] = f2bf(c0.z); af.u[3] = f2bf(c0.w);
      af.u[4] = f2bf(c1.x); af.u[5] = f2bf(c1.y);
      af.u[6] = f2bf(c1.z); af.u[7] = f2bf(c1.w);
      acc[mt][0] = __builtin_amdgcn_mfma_f32_16x16x32_bf16(af.v, bf[0].v, acc[mt][0], 0, 0, 0);
      acc[mt][1] = __builtin_amdgcn_mfma_f32_16x16x32_bf16(af.v, bf[1].v, acc[mt][1], 0, 0, 0);
    }
  }
  float* slab = partial + (long)j * (B * HID);
#pragma unroll
  for (int mt = 0; mt < 4; ++mt)
#pragma unroll
    for (int ntl = 0; ntl < 2; ++ntl)
#pragma unroll
      for (int r = 0; r < 4; ++r) {
        int g = mt * 16 + quad * 4 + r;
        int ch = (wid * 2 + ntl) * 16 + m16;
        slab[g * HID + ch] = acc[mt][ntl][r];
      }
}

__global__ __launch_bounds__(256) void k_pool_reduce(const float* __restrict__ partial,
                                                     float* __restrict__ pooled) {
  __shared__ float s[256];
  const int ol = threadIdx.x & 31, jl = threadIdx.x >> 5;
  const int o = blockIdx.x * 32 + ol;
  float acc = 0.f;
  for (int j = jl; j < NBUK; j += 8)
    acc += partial[(long)j * (B * HID) + o];
  s[threadIdx.x] = acc;
  __syncthreads();
  if (threadIdx.x < 32) {
    float a = s[threadIdx.x];
#pragma unroll
    for (int k = 1; k < 8; ++k) a += s[k * 32 + threadIdx.x];
    pooled[o] = a;
  }
}

// ---------------- final GEMM ----------------

__global__ __launch_bounds__(256) void k_final(const float* __restrict__ pooled,
                                               const int* __restrict__ starts,
                                               const float* __restrict__ W3,
                                               const float* __restrict__ b3,
                                               float* __restrict__ out) {
  __shared__ float p[HID];
  int g = blockIdx.x, tid = threadIdx.x;
  int len = starts[g + 1] - starts[g];
  float scale = 1.0f / fmaxf((float)len, 1.0f);
  if (tid < HID) p[tid] = pooled[g * HID + tid] * scale;
  __syncthreads();
  float a = b3[tid];
  for (int k = 0; k < HID; ++k) a = fmaf(p[k], W3[k * OUTD + tid], a);
  out[g * OUTD + tid] = a;
}

// ---------------- launch ----------------

extern "C" void kernel_launch(void* const* d_in, const int* in_sizes, int n_in,
                              void* d_out, int out_size, void* d_ws, size_t ws_size,
                              hipStream_t stream) {
  const float* x    = (const float*)d_in[0];
  const int*   eidx = (const int*)d_in[1];
  const int*   batch= (const int*)d_in[2];
  const float* W1   = (const float*)d_in[3];
  const float* b1   = (const float*)d_in[4];
  const float* W2   = (const float*)d_in[5];
  const float* b2   = (const float*)d_in[6];
  const float* W3   = (const float*)d_in[7];
  const float* b3   = (const float*)d_in[8];
  const float* resW = (const float*)d_in[9];
  const float* resb = (const float*)d_in[10];
  const float* g1   = (const float*)d_in[11];
  const float* bb1  = (const float*)d_in[12];
  const float* g2   = (const float*)d_in[13];
  const float* bb2  = (const float*)d_in[14];
  float* out = (float*)d_out;

  char* w = (char*)d_ws;
  size_t off = 0;
  auto alloc = [&](size_t bytes) {
    char* p = w + off;
    off = (off + bytes + 1023) & ~(size_t)1023;
    return p;
  };
  float* dinv   = (float*)alloc((size_t)N * 4);
  int*   rowptr = (int*)alloc((size_t)(N + 1) * 4);
  int*   colsrc = (int*)alloc((size_t)E * 4);
  int*   ebuf   = (int*)alloc((size_t)E * 4);
  int*   ebuf2  = (int*)alloc((size_t)E * 4);
  int*   hist   = (int*)alloc((size_t)GB * NBUK * 4);
  int*   hist2  = (int*)alloc((size_t)GB * NBUK * 4);
  int*   btotal = (int*)alloc((size_t)NBUK * 4);
  int*   btotal2= (int*)alloc((size_t)NBUK * 4);
  int*   bexcl  = (int*)alloc((size_t)(NBUK + 1) * 4);
  int*   bexcl2 = (int*)alloc((size_t)(NBUK + 1) * 4);
  int*   starts = (int*)alloc((size_t)(B + 1) * 4);
  float* pooled = (float*)alloc((size_t)B * HID * 4);
  ushort_t* aggx16 = (ushort_t*)alloc((size_t)N * IND * 2);
  ushort_t* xs16   = (ushort_t*)alloc((size_t)N * IND * 2);
  ushort_t* wpack  = (ushort_t*)alloc((size_t)HID * HID * 2);
  ushort_t* w1pack = (ushort_t*)alloc((size_t)8192 * 2);
  unsigned char* h8a = (unsigned char*)alloc((size_t)N * HID);
  unsigned char* h8b = (unsigned char*)alloc((size_t)N * HID);
  float* partial = (float*)alloc((size_t)NBUK * B * HID * 4);   // 25.6 MB

  // ---- prep: seg starts, weight packs, dual-order CSR build ----
  k_seg_starts<<<(N + 255) / 256, 256, 0, stream>>>(batch, starts);
  k_pack<<<96, 256, 0, stream>>>(W2, W1, resW, wpack, w1pack);
  k_hist<<<GB, 256, 0, stream>>>(eidx, hist, hist2);
  k_bscan2x<<<2 * NBUK, 256, 0, stream>>>(hist, btotal, hist2, btotal2);
  k_bktscan2x<<<2, 256, 0, stream>>>(btotal, bexcl, btotal2, bexcl2, rowptr);
  k_scatter<<<GB, 256, 0, stream>>>(eidx, hist, bexcl, hist2, bexcl2, ebuf, ebuf2);
  k_csr<<<NBUK, 256, 0, stream>>>(ebuf, bexcl, x, rowptr, dinv, colsrc, xs16);

  // ---- layer 1: 20-dim gather (bf16 out), conv1 on MFMA + LN1 + ReLU ----
  k_gather20b<<<N / 25, 256, 0, stream>>>(xs16, dinv, rowptr, colsrc, aggx16);
  k_conv1m<<<N / 16, 256, 0, stream>>>(aggx16, x, w1pack, b1, resb,
                                       g1, bb1, dinv, h8a);

  // ---- layer 2: fp8 gather + MFMA GEMM + LN2 + ReLU, fp8 out ----
  k_layer2<<<N / 16, 256, 0, stream>>>(h8a, dinv, rowptr, colsrc,
                                       wpack, b2, g2, bb2, h8b);

  // ---- layer 3: dense per-bucket pool GEMM -> partial slabs -> reduce ----
  k_pool3m<<<NBUK, 256, 0, stream>>>(h8b, bexcl2, ebuf2, batch, dinv, partial);
  k_pool_reduce<<<(B * HID) / 32, 256, 0, stream>>>(partial, pooled);
  k_final<<<B, 256, 0, stream>>>(pooled, starts, W3, b3, out);
}

// Round 16
// 306.334 us; speedup vs baseline: 1.3166x; 1.1103x over previous
//
#include <hip/hip_runtime.h>
#include <hip/hip_bf16.h>
#include <hip/hip_fp16.h>
#include <hip/hip_fp8.h>

// GCN: N=100000 nodes, E=1600000 edges, B=64 graphs, 20 -> 128 -> 128 -> 256.
// Strategy log:
//  - gcn_conv(h,W) = (scatter_norm(h)) @ W; mean-pool commutes with W3.
//  - R1 sorted-batch seg starts; R3 two-level bucket-sort CSR.
//  - R4-R8: gathers pinned by random line traffic; fp8 payloads (R7).
//  - R9 lesson: edge-parallel scatter or bust. R11: layer2 GEMM on MFMA.
//  - R12/13: layer-3 -> dense per-bucket GEMM + partial slabs + reduce.
//  - R14: fp8-only residual (h16a deleted); conv1 on MFMA; launch merges.
//  - R15: layer2 gather restructured: one ROW per 16-lane group (16 lanes x 8B
//    = full 128B fp8 row per edge-load). 4 rows/wave in PARALLEL (was serial
//    r-loop), no cross-lane reduce (lanes own disjoint channels), unroll 4
//    -> ~4x fewer dependent latency stages per wave.

typedef unsigned short ushort_t;
typedef unsigned int uint_t;
typedef __attribute__((ext_vector_type(8))) short bf16x8;
typedef __attribute__((ext_vector_type(4))) float f32x4;

constexpr int N  = 100000;
constexpr int E  = 1600000;
constexpr int B  = 64;
constexpr int IND = 20;
constexpr int HID = 128;
constexpr int OUTD = 256;

constexpr int NBUK = (N + 127) / 128;   // 782 buckets of 128 nodes
constexpr int GB   = 256;               // hist/scatter blocks
constexpr int EPB  = E / GB;            // 6250 edges per block
constexpr int BMAX = 3072;              // LDS cap per bucket (mean 2048, sd ~45)

// bf16 helpers (RNE pack, shift-unpack)
__device__ inline ushort_t f2bf(float f) {
  union { float f; uint_t u; } v; v.f = f;
  uint_t r = v.u + 0x7fffu + ((v.u >> 16) & 1u);
  return (ushort_t)(r >> 16);
}
__device__ inline float bflo(uint_t u) { return __uint_as_float(u << 16); }
__device__ inline float bfhi(uint_t u) { return __uint_as_float(u & 0xffff0000u); }

// fp8 e4m3 helpers (HW cvt on gfx950; hip_fp8.h fallback)
#if defined(__has_builtin)
#if __has_builtin(__builtin_amdgcn_cvt_f32_fp8) && __has_builtin(__builtin_amdgcn_cvt_pk_fp8_f32)
#define FP8_HW 1
#endif
#endif

template <int S>
__device__ inline float fp8dec(uint_t u) {
#ifdef FP8_HW
  return __builtin_amdgcn_cvt_f32_fp8(u, S);
#else
  __hip_fp8_storage_t b = (__hip_fp8_storage_t)((u >> (8 * S)) & 0xffu);
  __half_raw hr = __hip_cvt_fp8_to_halfraw(b, __HIP_E4M3);
  return __half2float(*(__half*)&hr);
#endif
}

template <bool W>
__device__ inline uint_t fp8pk2(float a, float b, uint_t old) {
#ifdef FP8_HW
  return __builtin_amdgcn_cvt_pk_fp8_f32(a, b, old, W);
#else
  uint_t lo = (uint_t)__hip_cvt_float_to_fp8(a, __HIP_SATFINITE, __HIP_E4M3);
  uint_t hi = (uint_t)__hip_cvt_float_to_fp8(b, __HIP_SATFINITE, __HIP_E4M3);
  uint_t pair = lo | (hi << 8);
  return W ? ((old & 0x0000ffffu) | (pair << 16)) : ((old & 0xffff0000u) | pair);
#endif
}

__device__ inline unsigned char fp8enc1(float a) {
  return (unsigned char)(fp8pk2<false>(a, a, 0u) & 0xffu);
}

// decode 8 fp8 (uint2) into a[0..7]
#define FP8DEC8(u, a0, a1, a2, a3, a4, a5, a6, a7) \
  { a0 = fp8dec<0>(u.x); a1 = fp8dec<1>(u.x); a2 = fp8dec<2>(u.x); a3 = fp8dec<3>(u.x); \
    a4 = fp8dec<0>(u.y); a5 = fp8dec<1>(u.y); a6 = fp8dec<2>(u.y); a7 = fp8dec<3>(u.y); }

// ---------------- init + segment starts ----------------

__global__ __launch_bounds__(256) void k_seg_starts(const int* __restrict__ batch,
                                                    int* __restrict__ starts) {
  int i = blockIdx.x * 256 + threadIdx.x;
  if (i >= N) return;
  int b = batch[i];
  int prev = (i == 0) ? -1 : batch[i - 1];
  for (int g = prev + 1; g <= b; ++g) starts[g] = i;  // fires only at boundaries
  if (i == N - 1)
    for (int g = b + 1; g <= B; ++g) starts[g] = N;
}

// Pack W2 into MFMA B-frag order (16384 entries) AND [W1|resW] K=64 pack
// (8192 entries). B-frag: lane&15 = n, (lane>>4)*8+j = k-within-ktile.
__global__ __launch_bounds__(256) void k_pack(const float* __restrict__ W2,
                                              const float* __restrict__ W1,
                                              const float* __restrict__ resW,
                                              ushort_t* __restrict__ wpack,
                                              ushort_t* __restrict__ w1pack) {
  int idx = blockIdx.x * 256 + threadIdx.x;   // 96 blocks = 24576
  if (idx < 16384) {
    int j = idx & 7, L = (idx >> 3) & 63, kt = (idx >> 9) & 3, t = idx >> 11;
    int k = kt * 32 + ((L >> 4) & 3) * 8 + j;
    int n = t * 16 + (L & 15);
    wpack[idx] = f2bf(W2[k * HID + n]);
  } else {
    int i2 = idx - 16384;
    int j = i2 & 7, L = (i2 >> 3) & 63, kt = (i2 >> 9) & 1, t = i2 >> 10;
    int k = kt * 32 + ((L >> 4) & 3) * 8 + j;
    int n = t * 16 + (L & 15);
    float v = 0.f;
    if (k < IND) v = W1[k * HID + n];
    else if (k >= 32 && k < 32 + IND) v = resW[(k - 32) * HID + n];
    w1pack[i2] = f2bf(v);
  }
}

// ---------------- CSR builds: bucket sorts by dst AND by src ----------------

__global__ __launch_bounds__(256) void k_hist(const int* __restrict__ eidx,
                                              int* __restrict__ histd,
                                              int* __restrict__ hists) {
  __shared__ int hd[NBUK], hs[NBUK];
  for (int i = threadIdx.x; i < NBUK; i += 256) { hd[i] = 0; hs[i] = 0; }
  __syncthreads();
  const long base = (long)blockIdx.x * EPB;
  for (int i = threadIdx.x; i < EPB; i += 256) {
    atomicAdd(&hs[eidx[base + i] >> 7], 1);
    atomicAdd(&hd[eidx[E + base + i] >> 7], 1);
  }
  __syncthreads();
  for (int i = threadIdx.x; i < NBUK; i += 256) {
    histd[(long)blockIdx.x * NBUK + i] = hd[i];
    hists[(long)blockIdx.x * NBUK + i] = hs[i];
  }
}

// Both per-bucket scans in one launch: grid = 2*NBUK.
__global__ __launch_bounds__(256) void k_bscan2x(int* __restrict__ histd,
                                                 int* __restrict__ btd,
                                                 int* __restrict__ hists,
                                                 int* __restrict__ bts) {
  __shared__ int s[256];
  const int which = (blockIdx.x >= NBUK);
  const int j = which ? blockIdx.x - NBUK : blockIdx.x;
  int* hist = which ? hists : histd;
  int* btotal = which ? bts : btd;
  const int tid = threadIdx.x;
  int v = hist[(long)tid * NBUK + j];
  s[tid] = v;
  for (int off = 1; off < 256; off <<= 1) {
    __syncthreads();
    int x = (tid >= off) ? s[tid - off] : 0;
    __syncthreads();
    s[tid] += x;
  }
  hist[(long)tid * NBUK + j] = s[tid] - v;   // exclusive within bucket
  if (tid == 255) btotal[j] = s[255];
}

// Both bucket-total scans in one launch: grid = 2.
__global__ __launch_bounds__(256) void k_bktscan2x(const int* __restrict__ btd,
                                                   int* __restrict__ bexcl,
                                                   const int* __restrict__ bts,
                                                   int* __restrict__ bexcl2,
                                                   int* __restrict__ rowptr) {
  __shared__ int s[256];
  const int* bt = blockIdx.x ? bts : btd;
  int* bx = blockIdx.x ? bexcl2 : bexcl;
  int tid = threadIdx.x;
  int base = tid * 4;
  int v0 = (base + 0 < NBUK) ? bt[base + 0] : 0;
  int v1 = (base + 1 < NBUK) ? bt[base + 1] : 0;
  int v2 = (base + 2 < NBUK) ? bt[base + 2] : 0;
  int v3 = (base + 3 < NBUK) ? bt[base + 3] : 0;
  int p0 = v0, p1 = p0 + v1, p2 = p1 + v2, p3 = p2 + v3;
  s[tid] = p3;
  for (int off = 1; off < 256; off <<= 1) {
    __syncthreads();
    int x = (tid >= off) ? s[tid - off] : 0;
    __syncthreads();
    s[tid] += x;
  }
  int excl = s[tid] - p3;
  if (base + 0 < NBUK) bx[base + 1] = excl + p0;
  if (base + 1 < NBUK) bx[base + 2] = excl + p1;
  if (base + 2 < NBUK) bx[base + 3] = excl + p2;
  if (base + 3 < NBUK) bx[base + 4] = excl + p3;
  if (tid == 0) { bx[0] = 0; if (blockIdx.x == 0) rowptr[N] = E; }
}

// Merged scatter: ONE edge pass writes BOTH orderings.
// ebuf (dst-order):  src(20b) | dstlow(7b)<<20
// ebuf2 (src-order): srclow(7b)<<17 | dst(17b)
__global__ __launch_bounds__(256) void k_scatter(const int* __restrict__ eidx,
                                                 const int* __restrict__ histd,
                                                 const int* __restrict__ bexcl,
                                                 const int* __restrict__ hists,
                                                 const int* __restrict__ bexcl2,
                                                 int* __restrict__ ebuf,
                                                 int* __restrict__ ebuf2) {
  __shared__ int hd[NBUK], hs[NBUK];
  for (int i = threadIdx.x; i < NBUK; i += 256) {
    hd[i] = bexcl[i] + histd[(long)blockIdx.x * NBUK + i];
    hs[i] = bexcl2[i] + hists[(long)blockIdx.x * NBUK + i];
  }
  __syncthreads();
  const long base = (long)blockIdx.x * EPB;
  for (int i = threadIdx.x; i < EPB; i += 256) {
    int s = eidx[base + i];
    int d = eidx[E + base + i];
    int pos = atomicAdd(&hd[d >> 7], 1);
    ebuf[pos] = s | ((d & 127) << 20);
    int pos2 = atomicAdd(&hs[s >> 7], 1);
    ebuf2[pos2] = ((s & 127) << 17) | d;
  }
}

// One block per dst-bucket: LDS counting sort -> rowptr/dinv/colsrc + xs16.
__global__ __launch_bounds__(256) void k_csr(const int* __restrict__ ebuf,
                                             const int* __restrict__ bexcl,
                                             const float* __restrict__ x,
                                             int* __restrict__ rowptr,
                                             float* __restrict__ dinv,
                                             int* __restrict__ colsrc,
                                             ushort_t* __restrict__ xs16) {
  __shared__ int deg[128], s[128], cur[128];
  __shared__ float dv[128];
  __shared__ int lout[BMAX];
  const int j = blockIdx.x, tid = threadIdx.x;
  const int e0 = bexcl[j], e1 = bexcl[j + 1];
  const int cnt = e1 - e0;
  if (tid < 128) deg[tid] = 0;
  __syncthreads();
  for (int i = tid; i < cnt; i += 256)
    atomicAdd(&deg[(ebuf[e0 + i] >> 20) & 127], 1);
  __syncthreads();
  int v = (tid < 128) ? deg[tid] : 0;
  if (tid < 128) s[tid] = v;
  for (int off = 1; off < 128; off <<= 1) {
    __syncthreads();
    int x2 = (tid < 128 && tid >= off) ? s[tid - off] : 0;
    __syncthreads();
    if (tid < 128) s[tid] += x2;
  }
  __syncthreads();
  if (tid < 128) {
    int ex = s[tid] - v;
    cur[tid] = ex;
    float d = rsqrtf((float)(1 + v));   // deg includes self-loop
    dv[tid] = d;
    int node = j * 128 + tid;
    if (node < N) {
      rowptr[node] = e0 + ex;
      dinv[node] = d;
    }
  }
  __syncthreads();
  if (cnt <= BMAX) {
    for (int i = tid; i < cnt; i += 256) {
      int p = ebuf[e0 + i];
      int pos = atomicAdd(&cur[(p >> 20) & 127], 1);
      lout[pos] = p & 0xFFFFF;
    }
    __syncthreads();
    for (int i = tid; i < cnt; i += 256) colsrc[e0 + i] = lout[i];
  } else {  // safety fallback
    for (int i = tid; i < cnt; i += 256) {
      int p = ebuf[e0 + i];
      int pos = atomicAdd(&cur[(p >> 20) & 127], 1);
      colsrc[e0 + pos] = p & 0xFFFFF;
    }
  }
  for (int idx = tid; idx < 128 * IND; idx += 256) {
    int n = idx / IND;
    long node = (long)j * 128 + n;
    if (node < N)
      xs16[node * IND + idx % IND] = f2bf(x[node * IND + idx % IND] * dv[n]);
  }
}

// ---------------- layer 1 ----------------

// 20-dim gather over bf16 x*dinv rows: 10 threads/node, 2 channels each.
__global__ __launch_bounds__(256) void k_gather20b(const ushort_t* __restrict__ xs16,
                                                   const float* __restrict__ dinv,
                                                   const int* __restrict__ rowptr,
                                                   const int* __restrict__ colsrc,
                                                   ushort_t* __restrict__ aggx16) {
  int t = threadIdx.x;
  if (t >= 250) return;
  int n = t / 10, cc = (t % 10) * 2;
  long i = (long)blockIdx.x * 25 + n;               // grid = N/25 exact
  float di = dinv[i];
  uint_t u = *(const uint_t*)(xs16 + i * IND + cc);
  float a0 = bflo(u), a1 = bfhi(u);
  int e0 = rowptr[i], e1 = rowptr[i + 1];
#pragma unroll 4
  for (int e = e0; e < e1; ++e) {
    int s = colsrc[e];
    uint_t v = *(const uint_t*)(xs16 + (long)s * IND + cc);
    a0 += bflo(v); a1 += bfhi(v);
  }
  uint_t p0 = f2bf(a0 * di), p1 = f2bf(a1 * di);
  *(uint_t*)&aggx16[i * IND + cc] = p0 | (p1 << 16);
}

// conv1 on MFMA: h1 = relu(LN1([aggx|x] @ [W1;resW] + b1 + resb)).
constexpr int ASTR = 72;    // bf16 A stride
constexpr int CSTR = 132;   // fp32 C stride

__global__ __launch_bounds__(256) void k_conv1m(const ushort_t* __restrict__ aggx16,
                                                const float* __restrict__ x,
                                                const ushort_t* __restrict__ w1pack,
                                                const float* __restrict__ b1,
                                                const float* __restrict__ resb,
                                                const float* __restrict__ g1,
                                                const float* __restrict__ bb1,
                                                const float* __restrict__ dinv,
                                                unsigned char* __restrict__ h8a) {
  __shared__ ushort_t A[16 * ASTR];   // 2.25 KB
  __shared__ float Cs[16 * CSTR];     // 8.25 KB
  const int tid = threadIdx.x;
  const long node0 = (long)blockIdx.x * 16;           // grid = N/16 exact
  for (int idx = tid; idx < 16 * 64; idx += 256) {
    int n = idx >> 6, k = idx & 63;
    ushort_t v = 0;
    if (k < IND) v = aggx16[(node0 + n) * IND + k];
    else if (k >= 32 && k < 32 + IND) v = f2bf(x[(node0 + n) * IND + (k - 32)]);
    A[n * ASTR + k] = v;
  }
  __syncthreads();
  const int lane = tid & 63, w = tid >> 6;
  {
    const int arow = lane & 15, aq = lane >> 4;
    f32x4 acc0 = {0.f, 0.f, 0.f, 0.f}, acc1 = {0.f, 0.f, 0.f, 0.f};
    const int t0 = w * 2, t1 = t0 + 1;
#pragma unroll
    for (int kt = 0; kt < 2; ++kt) {
      bf16x8 af = *(const bf16x8*)&A[arow * ASTR + kt * 32 + aq * 8];
      bf16x8 b0 = *(const bf16x8*)&w1pack[(t0 * 2 + kt) * 512 + lane * 8];
      bf16x8 b1f = *(const bf16x8*)&w1pack[(t1 * 2 + kt) * 512 + lane * 8];
      acc0 = __builtin_amdgcn_mfma_f32_16x16x32_bf16(af, b0, acc0, 0, 0, 0);
      acc1 = __builtin_amdgcn_mfma_f32_16x16x32_bf16(af, b1f, acc1, 0, 0, 0);
    }
#pragma unroll
    for (int r = 0; r < 4; ++r) {
      Cs[(aq * 4 + r) * CSTR + t0 * 16 + arow] = acc0[r];
      Cs[(aq * 4 + r) * CSTR + t1 * 16 + arow] = acc1[r];
    }
  }
  __syncthreads();
  const int nidx = tid >> 5, col = (tid & 31) * 4;
  float4 bz = *(const float4*)&b1[col];
  float4 rz = *(const float4*)&resb[col];
  bz.x += rz.x; bz.y += rz.y; bz.z += rz.z; bz.w += rz.w;
  float4 gz = *(const float4*)&g1[col];
  float4 bbz = *(const float4*)&bb1[col];
#pragma unroll
  for (int m = 0; m < 2; ++m) {
    int nl = nidx + m * 8;
    long nm = node0 + nl;
    float4 o = *(const float4*)&Cs[nl * CSTR + col];
    o.x += bz.x; o.y += bz.y; o.z += bz.z; o.w += bz.w;
    float s = o.x + o.y + o.z + o.w;
    float q = o.x * o.x + o.y * o.y + o.z * o.z + o.w * o.w;
#pragma unroll
    for (int off = 1; off <= 16; off <<= 1) {
      s += __shfl_xor(s, off);
      q += __shfl_xor(q, off);
    }
    float mu = s * (1.f / 128.f);
    float var = q * (1.f / 128.f) - mu * mu;
    float rs = rsqrtf(var + 1e-5f);
    float y0 = fmaxf(fmaf((o.x - mu) * rs, gz.x, bbz.x), 0.f);
    float y1 = fmaxf(fmaf((o.y - mu) * rs, gz.y, bbz.y), 0.f);
    float y2 = fmaxf(fmaf((o.z - mu) * rs, gz.z, bbz.z), 0.f);
    float y3 = fmaxf(fmaf((o.w - mu) * rs, gz.w, bbz.w), 0.f);
    float di = dinv[nm];
    uint_t p = fp8pk2<false>(y0 * di, y1 * di, 0u);
    p = fp8pk2<true>(y2 * di, y3 * di, p);
    *(uint_t*)&h8a[nm * HID + col] = p;
  }
}

// ---------------- layer 2: fp8 gather + MFMA GEMM + LN + ReLU ----------------

constexpr int XSTR = 136;   // bf16 stride

__global__ __launch_bounds__(256) void k_layer2(const unsigned char* __restrict__ h8a,
                                                const float* __restrict__ dinv,
                                                const int* __restrict__ rowptr,
                                                const int* __restrict__ colsrc,
                                                const ushort_t* __restrict__ wpack,
                                                const float* __restrict__ bias,
                                                const float* __restrict__ g2,
                                                const float* __restrict__ bb2,
                                                unsigned char* __restrict__ h8b) {
  __shared__ ushort_t XsB[16 * XSTR];   // 4.25 KB bf16 gathered X
  __shared__ float Cs[16 * CSTR];       // 8.25 KB fp32 GEMM out
  const int tid = threadIdx.x;
  const long node0 = (long)blockIdx.x * 16;           // grid = N/16 exact
  const int lane = tid & 63, w = tid >> 6;
  // ---- phase 1: one ROW per 16-lane group; 16 lanes x 8B = full fp8 row.
  //      4 rows per wave in parallel; no cross-lane reduce; unroll 4. ----
  {
    const int grp = lane >> 4, l16 = lane & 15, c8 = l16 * 8;
    const long i = node0 + w * 4 + grp;
    const float di = dinv[i];
    float a0, a1, a2, a3, a4, a5, a6, a7;
    {   // self term (row already carries dinv[i])
      uint2 u = *(const uint2*)(h8a + i * HID + c8);
      FP8DEC8(u, a0, a1, a2, a3, a4, a5, a6, a7);
    }
    const int e0 = rowptr[i], e1 = rowptr[i + 1];
#pragma unroll 4
    for (int e = e0; e < e1; ++e) {
      int s = colsrc[e];
      uint2 u = *(const uint2*)(h8a + (long)s * HID + c8);
      float b0, b1, b2, b3, b4, b5, b6, b7;
      FP8DEC8(u, b0, b1, b2, b3, b4, b5, b6, b7);
      a0 += b0; a1 += b1; a2 += b2; a3 += b3;
      a4 += b4; a5 += b5; a6 += b6; a7 += b7;
    }
    uint_t p0 = (uint_t)f2bf(a0 * di) | ((uint_t)f2bf(a1 * di) << 16);
    uint_t p1 = (uint_t)f2bf(a2 * di) | ((uint_t)f2bf(a3 * di) << 16);
    uint_t p2 = (uint_t)f2bf(a4 * di) | ((uint_t)f2bf(a5 * di) << 16);
    uint_t p3 = (uint_t)f2bf(a6 * di) | ((uint_t)f2bf(a7 * di) << 16);
    *(uint4*)&XsB[(w * 4 + grp) * XSTR + c8] = make_uint4(p0, p1, p2, p3);
  }
  __syncthreads();
  // ---- phase 2: MFMA. Wave w covers n-tiles {2w, 2w+1}. ----
  {
    const int arow = lane & 15, aq = lane >> 4;
    f32x4 acc0 = {0.f, 0.f, 0.f, 0.f}, acc1 = {0.f, 0.f, 0.f, 0.f};
    const int t0 = w * 2, t1 = w * 2 + 1;
#pragma unroll
    for (int kt = 0; kt < 4; ++kt) {
      bf16x8 af = *(const bf16x8*)&XsB[arow * XSTR + kt * 32 + aq * 8];
      bf16x8 b0 = *(const bf16x8*)&wpack[(t0 * 4 + kt) * 512 + lane * 8];
      bf16x8 b1 = *(const bf16x8*)&wpack[(t1 * 4 + kt) * 512 + lane * 8];
      acc0 = __builtin_amdgcn_mfma_f32_16x16x32_bf16(af, b0, acc0, 0, 0, 0);
      acc1 = __builtin_amdgcn_mfma_f32_16x16x32_bf16(af, b1, acc1, 0, 0, 0);
    }
#pragma unroll
    for (int r = 0; r < 4; ++r) {
      Cs[(aq * 4 + r) * CSTR + t0 * 16 + arow] = acc0[r];
      Cs[(aq * 4 + r) * CSTR + t1 * 16 + arow] = acc1[r];
    }
  }
  __syncthreads();
  // ---- phase 3: bias + residual(fp8 h8a) + LN + ReLU + fp8 store ----
  const int nidx = tid >> 5;
  const int col = (tid & 31) * 4;
  float4 bz = *(const float4*)&bias[col];
  float4 gz = *(const float4*)&g2[col];
  float4 bbz = *(const float4*)&bb2[col];
#pragma unroll
  for (int m = 0; m < 2; ++m) {
    int nl = nidx + m * 8;
    long nm = node0 + nl;
    float di = dinv[nm];
    float rdi = 1.0f / di;
    uint_t ur = *(const uint_t*)&h8a[nm * HID + col];   // fp8 residual (L2-hot)
    float4 o = *(const float4*)&Cs[nl * CSTR + col];
    o.x += bz.x + fp8dec<0>(ur) * rdi;
    o.y += bz.y + fp8dec<1>(ur) * rdi;
    o.z += bz.z + fp8dec<2>(ur) * rdi;
    o.w += bz.w + fp8dec<3>(ur) * rdi;
    float s = o.x + o.y + o.z + o.w;
    float q = o.x * o.x + o.y * o.y + o.z * o.z + o.w * o.w;
#pragma unroll
    for (int off = 1; off <= 16; off <<= 1) {
      s += __shfl_xor(s, off);
      q += __shfl_xor(q, off);
    }
    float mu = s * (1.f / 128.f);
    float var = q * (1.f / 128.f) - mu * mu;
    float rs = rsqrtf(var + 1e-5f);
    float y0 = fmaxf(fmaf((o.x - mu) * rs, gz.x, bbz.x), 0.f);
    float y1 = fmaxf(fmaf((o.y - mu) * rs, gz.y, bbz.y), 0.f);
    float y2 = fmaxf(fmaf((o.z - mu) * rs, gz.z, bbz.z), 0.f);
    float y3 = fmaxf(fmaf((o.w - mu) * rs, gz.w, bbz.w), 0.f);
    uint_t p = fp8pk2<false>(y0 * di, y1 * di, 0u);
    p = fp8pk2<true>(y2 * di, y3 * di, p);
    *(uint_t*)&h8b[nm * HID + col] = p;
  }
}

// ---------------- layer 3: per-bucket dense pool GEMM ----------------

constexpr int RSTR = 136;   // bf16 row stride for R
constexpr int CP   = 132;   // fp32 row stride for C

__global__ __launch_bounds__(256) void k_pool3m(const unsigned char* __restrict__ h8b,
                                                const int* __restrict__ bexcl2,
                                                const int* __restrict__ ebuf2,
                                                const int* __restrict__ batch,
                                                const float* __restrict__ dinv,
                                                float* __restrict__ partial) {
  __shared__ float Cm[B * CP];          // 33.8 KB
  __shared__ ushort_t R[128 * RSTR];    // 34.8 KB
  const int j = blockIdx.x, tid = threadIdx.x;
  const long nbase = (long)j * 128;
  const int validRows = min(128, N - (int)nbase);
  for (int i = tid; i < B * CP; i += 256) Cm[i] = 0.f;
  for (int i = tid; i < 128 * (HID / 8); i += 256) {
    int s = i >> 4;
    int ch = (i & 15) * 8;
    uint4 pk = make_uint4(0u, 0u, 0u, 0u);
    if (s < validRows) {
      uint2 u = *(const uint2*)(h8b + (nbase + s) * HID + ch);
      float b0, b1, b2, b3, b4, b5, b6, b7;
      FP8DEC8(u, b0, b1, b2, b3, b4, b5, b6, b7);
      pk.x = (uint_t)f2bf(b0) | ((uint_t)f2bf(b1) << 16);
      pk.y = (uint_t)f2bf(b2) | ((uint_t)f2bf(b3) << 16);
      pk.z = (uint_t)f2bf(b4) | ((uint_t)f2bf(b5) << 16);
      pk.w = (uint_t)f2bf(b6) | ((uint_t)f2bf(b7) << 16);
    }
    *(uint4*)&R[s * RSTR + ch] = pk;
  }
  __syncthreads();
  const int e0 = bexcl2[j], e1 = bexcl2[j + 1];
  for (int e = e0 + tid; e < e1; e += 256) {
    int p = ebuf2[e];
    int s = (p >> 17) & 127;
    int d = p & 0x1FFFF;
    atomicAdd(&Cm[batch[d] * CP + s], dinv[d]);
  }
  for (int n = tid; n < validRows; n += 256) {
    long node = nbase + n;
    atomicAdd(&Cm[batch[node] * CP + n], dinv[node]);   // self term
  }
  __syncthreads();
  const int lane = tid & 63, wid = tid >> 6;
  const int m16 = lane & 15, quad = lane >> 4;
  f32x4 acc[4][2];
#pragma unroll
  for (int mt = 0; mt < 4; ++mt)
#pragma unroll
    for (int ntl = 0; ntl < 2; ++ntl) acc[mt][ntl] = (f32x4){0.f, 0.f, 0.f, 0.f};
#pragma unroll
  for (int kt = 0; kt < 4; ++kt) {
    union { ushort_t u[8]; bf16x8 v; } bf[2];
#pragma unroll
    for (int ntl = 0; ntl < 2; ++ntl) {
      int nt = wid * 2 + ntl;
#pragma unroll
      for (int jj = 0; jj < 8; ++jj)
        bf[ntl].u[jj] = R[(kt * 32 + quad * 8 + jj) * RSTR + nt * 16 + m16];
    }
#pragma unroll
    for (int mt = 0; mt < 4; ++mt) {
      float4 c0 = *(const float4*)&Cm[(mt * 16 + m16) * CP + kt * 32 + quad * 8];
      float4 c1 = *(const float4*)&Cm[(mt * 16 + m16) * CP + kt * 32 + quad * 8 + 4];
      union { ushort_t u[8]; bf16x8 v; } af;
      af.u[0] = f2bf(c0.x); af.u[1] = f2bf(c0.y);
      af.u[2] = f2bf(c0.z); af.u[3] = f2bf(c0.w);
      af.u[4] = f2bf(c1.x); af.u[5] = f2bf(c1.y);
      af.u[6] = f2bf(c1.z); af.u[7] = f2bf(c1.w);
      acc[mt][0] = __builtin_amdgcn_mfma_f32_16x16x32_bf16(af.v, bf[0].v, acc[mt][0], 0, 0, 0);
      acc[mt][1] = __builtin_amdgcn_mfma_f32_16x16x32_bf16(af.v, bf[1].v, acc[mt][1], 0, 0, 0);
    }
  }
  float* slab = partial + (long)j * (B * HID);
#pragma unroll
  for (int mt = 0; mt < 4; ++mt)
#pragma unroll
    for (int ntl = 0; ntl < 2; ++ntl)
#pragma unroll
      for (int r = 0; r < 4; ++r) {
        int g = mt * 16 + quad * 4 + r;
        int ch = (wid * 2 + ntl) * 16 + m16;
        slab[g * HID + ch] = acc[mt][ntl][r];
      }
}

__global__ __launch_bounds__(256) void k_pool_reduce(const float* __restrict__ partial,
                                                     float* __restrict__ pooled) {
  __shared__ float s[256];
  const int ol = threadIdx.x & 31, jl = threadIdx.x >> 5;
  const int o = blockIdx.x * 32 + ol;
  float acc = 0.f;
  for (int j = jl; j < NBUK; j += 8)
    acc += partial[(long)j * (B * HID) + o];
  s[threadIdx.x] = acc;
  __syncthreads();
  if (threadIdx.x < 32) {
    float a = s[threadIdx.x];
#pragma unroll
    for (int k = 1; k < 8; ++k) a += s[k * 32 + threadIdx.x];
    pooled[o] = a;
  }
}

// ---------------- final GEMM ----------------

__global__ __launch_bounds__(256) void k_final(const float* __restrict__ pooled,
                                               const int* __restrict__ starts,
                                               const float* __restrict__ W3,
                                               const float* __restrict__ b3,
                                               float* __restrict__ out) {
  __shared__ float p[HID];
  int g = blockIdx.x, tid = threadIdx.x;
  int len = starts[g + 1] - starts[g];
  float scale = 1.0f / fmaxf((float)len, 1.0f);
  if (tid < HID) p[tid] = pooled[g * HID + tid] * scale;
  __syncthreads();
  float a = b3[tid];
  for (int k = 0; k < HID; ++k) a = fmaf(p[k], W3[k * OUTD + tid], a);
  out[g * OUTD + tid] = a;
}

// ---------------- launch ----------------

extern "C" void kernel_launch(void* const* d_in, const int* in_sizes, int n_in,
                              void* d_out, int out_size, void* d_ws, size_t ws_size,
                              hipStream_t stream) {
  const float* x    = (const float*)d_in[0];
  const int*   eidx = (const int*)d_in[1];
  const int*   batch= (const int*)d_in[2];
  const float* W1   = (const float*)d_in[3];
  const float* b1   = (const float*)d_in[4];
  const float* W2   = (const float*)d_in[5];
  const float* b2   = (const float*)d_in[6];
  const float* W3   = (const float*)d_in[7];
  const float* b3   = (const float*)d_in[8];
  const float* resW = (const float*)d_in[9];
  const float* resb = (const float*)d_in[10];
  const float* g1   = (const float*)d_in[11];
  const float* bb1  = (const float*)d_in[12];
  const float* g2   = (const float*)d_in[13];
  const float* bb2  = (const float*)d_in[14];
  float* out = (float*)d_out;

  char* w = (char*)d_ws;
  size_t off = 0;
  auto alloc = [&](size_t bytes) {
    char* p = w + off;
    off = (off + bytes + 1023) & ~(size_t)1023;
    return p;
  };
  float* dinv   = (float*)alloc((size_t)N * 4);
  int*   rowptr = (int*)alloc((size_t)(N + 1) * 4);
  int*   colsrc = (int*)alloc((size_t)E * 4);
  int*   ebuf   = (int*)alloc((size_t)E * 4);
  int*   ebuf2  = (int*)alloc((size_t)E * 4);
  int*   hist   = (int*)alloc((size_t)GB * NBUK * 4);
  int*   hist2  = (int*)alloc((size_t)GB * NBUK * 4);
  int*   btotal = (int*)alloc((size_t)NBUK * 4);
  int*   btotal2= (int*)alloc((size_t)NBUK * 4);
  int*   bexcl  = (int*)alloc((size_t)(NBUK + 1) * 4);
  int*   bexcl2 = (int*)alloc((size_t)(NBUK + 1) * 4);
  int*   starts = (int*)alloc((size_t)(B + 1) * 4);
  float* pooled = (float*)alloc((size_t)B * HID * 4);
  ushort_t* aggx16 = (ushort_t*)alloc((size_t)N * IND * 2);
  ushort_t* xs16   = (ushort_t*)alloc((size_t)N * IND * 2);
  ushort_t* wpack  = (ushort_t*)alloc((size_t)HID * HID * 2);
  ushort_t* w1pack = (ushort_t*)alloc((size_t)8192 * 2);
  unsigned char* h8a = (unsigned char*)alloc((size_t)N * HID);
  unsigned char* h8b = (unsigned char*)alloc((size_t)N * HID);
  float* partial = (float*)alloc((size_t)NBUK * B * HID * 4);   // 25.6 MB

  // ---- prep: seg starts, weight packs, dual-order CSR build ----
  k_seg_starts<<<(N + 255) / 256, 256, 0, stream>>>(batch, starts);
  k_pack<<<96, 256, 0, stream>>>(W2, W1, resW, wpack, w1pack);
  k_hist<<<GB, 256, 0, stream>>>(eidx, hist, hist2);
  k_bscan2x<<<2 * NBUK, 256, 0, stream>>>(hist, btotal, hist2, btotal2);
  k_bktscan2x<<<2, 256, 0, stream>>>(btotal, bexcl, btotal2, bexcl2, rowptr);
  k_scatter<<<GB, 256, 0, stream>>>(eidx, hist, bexcl, hist2, bexcl2, ebuf, ebuf2);
  k_csr<<<NBUK, 256, 0, stream>>>(ebuf, bexcl, x, rowptr, dinv, colsrc, xs16);

  // ---- layer 1: 20-dim gather (bf16 out), conv1 on MFMA + LN1 + ReLU ----
  k_gather20b<<<N / 25, 256, 0, stream>>>(xs16, dinv, rowptr, colsrc, aggx16);
  k_conv1m<<<N / 16, 256, 0, stream>>>(aggx16, x, w1pack, b1, resb,
                                       g1, bb1, dinv, h8a);

  // ---- layer 2: fp8 gather + MFMA GEMM + LN2 + ReLU, fp8 out ----
  k_layer2<<<N / 16, 256, 0, stream>>>(h8a, dinv, rowptr, colsrc,
                                       wpack, b2, g2, bb2, h8b);

  // ---- layer 3: dense per-bucket pool GEMM -> partial slabs -> reduce ----
  k_pool3m<<<NBUK, 256, 0, stream>>>(h8b, bexcl2, ebuf2, batch, dinv, partial);
  k_pool_reduce<<<(B * HID) / 32, 256, 0, stream>>>(partial, pooled);
  k_final<<<B, 256, 0, stream>>>(pooled, starts, W3, b3, out);
}

// Round 17
// 302.088 us; speedup vs baseline: 1.3351x; 1.0141x over previous
//
#include <hip/hip_runtime.h>
#include <hip/hip_bf16.h>
#include <hip/hip_fp16.h>
#include <hip/hip_fp8.h>

// GCN: N=100000 nodes, E=1600000 edges, B=64 graphs, 20 -> 128 -> 128 -> 256.
// Strategy log:
//  - gcn_conv(h,W) = (scatter_norm(h)) @ W; mean-pool commutes with W3.
//  - R1 sorted-batch seg starts; R3 two-level bucket-sort CSR.
//  - R4-R8: gathers pinned by random line traffic; fp8 payloads (R7).
//  - R9 lesson: edge-parallel scatter or bust. R11/14: GEMMs on MFMA.
//  - R12/13: layer-3 -> dense per-bucket GEMM + partial slabs + reduce.
//  - R15: layer2 gather: one row per 16-lane group, rows parallel, no reduce
//    -> 81 -> 48us (at the 8-XCD compulsory line-fill floor ~44us).
//  - R16: pool3m stages R as raw fp8 (LDS 68.6->51KB, 2->3 blocks/CU);
//    partial slabs bf16 (25.6->12.8MB round trip); gather20b fused into
//    conv1 (k_layer1: gather -> LDS A-tile -> MFMA; aggx16 deleted).

typedef unsigned short ushort_t;
typedef unsigned int uint_t;
typedef __attribute__((ext_vector_type(8))) short bf16x8;
typedef __attribute__((ext_vector_type(4))) float f32x4;

constexpr int N  = 100000;
constexpr int E  = 1600000;
constexpr int B  = 64;
constexpr int IND = 20;
constexpr int HID = 128;
constexpr int OUTD = 256;

constexpr int NBUK = (N + 127) / 128;   // 782 buckets of 128 nodes
constexpr int GB   = 256;               // hist/scatter blocks
constexpr int EPB  = E / GB;            // 6250 edges per block
constexpr int BMAX = 3072;              // LDS cap per bucket (mean 2048, sd ~45)

// bf16 helpers (RNE pack, shift-unpack)
__device__ inline ushort_t f2bf(float f) {
  union { float f; uint_t u; } v; v.f = f;
  uint_t r = v.u + 0x7fffu + ((v.u >> 16) & 1u);
  return (ushort_t)(r >> 16);
}
__device__ inline float bflo(uint_t u) { return __uint_as_float(u << 16); }
__device__ inline float bfhi(uint_t u) { return __uint_as_float(u & 0xffff0000u); }

// fp8 e4m3 helpers (HW cvt on gfx950; hip_fp8.h fallback)
#if defined(__has_builtin)
#if __has_builtin(__builtin_amdgcn_cvt_f32_fp8) && __has_builtin(__builtin_amdgcn_cvt_pk_fp8_f32)
#define FP8_HW 1
#endif
#endif

template <int S>
__device__ inline float fp8dec(uint_t u) {
#ifdef FP8_HW
  return __builtin_amdgcn_cvt_f32_fp8(u, S);
#else
  __hip_fp8_storage_t b = (__hip_fp8_storage_t)((u >> (8 * S)) & 0xffu);
  __half_raw hr = __hip_cvt_fp8_to_halfraw(b, __HIP_E4M3);
  return __half2float(*(__half*)&hr);
#endif
}

template <bool W>
__device__ inline uint_t fp8pk2(float a, float b, uint_t old) {
#ifdef FP8_HW
  return __builtin_amdgcn_cvt_pk_fp8_f32(a, b, old, W);
#else
  uint_t lo = (uint_t)__hip_cvt_float_to_fp8(a, __HIP_SATFINITE, __HIP_E4M3);
  uint_t hi = (uint_t)__hip_cvt_float_to_fp8(b, __HIP_SATFINITE, __HIP_E4M3);
  uint_t pair = lo | (hi << 8);
  return W ? ((old & 0x0000ffffu) | (pair << 16)) : ((old & 0xffff0000u) | pair);
#endif
}

// decode 8 fp8 (uint2) into a[0..7]
#define FP8DEC8(u, a0, a1, a2, a3, a4, a5, a6, a7) \
  { a0 = fp8dec<0>(u.x); a1 = fp8dec<1>(u.x); a2 = fp8dec<2>(u.x); a3 = fp8dec<3>(u.x); \
    a4 = fp8dec<0>(u.y); a5 = fp8dec<1>(u.y); a6 = fp8dec<2>(u.y); a7 = fp8dec<3>(u.y); }

// ---------------- init + segment starts ----------------

__global__ __launch_bounds__(256) void k_seg_starts(const int* __restrict__ batch,
                                                    int* __restrict__ starts) {
  int i = blockIdx.x * 256 + threadIdx.x;
  if (i >= N) return;
  int b = batch[i];
  int prev = (i == 0) ? -1 : batch[i - 1];
  for (int g = prev + 1; g <= b; ++g) starts[g] = i;  // fires only at boundaries
  if (i == N - 1)
    for (int g = b + 1; g <= B; ++g) starts[g] = N;
}

// Pack W2 into MFMA B-frag order (16384 entries) AND [W1|resW] K=64 pack
// (8192 entries). B-frag: lane&15 = n, (lane>>4)*8+j = k-within-ktile.
__global__ __launch_bounds__(256) void k_pack(const float* __restrict__ W2,
                                              const float* __restrict__ W1,
                                              const float* __restrict__ resW,
                                              ushort_t* __restrict__ wpack,
                                              ushort_t* __restrict__ w1pack) {
  int idx = blockIdx.x * 256 + threadIdx.x;   // 96 blocks = 24576
  if (idx < 16384) {
    int j = idx & 7, L = (idx >> 3) & 63, kt = (idx >> 9) & 3, t = idx >> 11;
    int k = kt * 32 + ((L >> 4) & 3) * 8 + j;
    int n = t * 16 + (L & 15);
    wpack[idx] = f2bf(W2[k * HID + n]);
  } else {
    int i2 = idx - 16384;
    int j = i2 & 7, L = (i2 >> 3) & 63, kt = (i2 >> 9) & 1, t = i2 >> 10;
    int k = kt * 32 + ((L >> 4) & 3) * 8 + j;
    int n = t * 16 + (L & 15);
    float v = 0.f;
    if (k < IND) v = W1[k * HID + n];
    else if (k >= 32 && k < 32 + IND) v = resW[(k - 32) * HID + n];
    w1pack[i2] = f2bf(v);
  }
}

// ---------------- CSR builds: bucket sorts by dst AND by src ----------------

__global__ __launch_bounds__(256) void k_hist(const int* __restrict__ eidx,
                                              int* __restrict__ histd,
                                              int* __restrict__ hists) {
  __shared__ int hd[NBUK], hs[NBUK];
  for (int i = threadIdx.x; i < NBUK; i += 256) { hd[i] = 0; hs[i] = 0; }
  __syncthreads();
  const long base = (long)blockIdx.x * EPB;
  for (int i = threadIdx.x; i < EPB; i += 256) {
    atomicAdd(&hs[eidx[base + i] >> 7], 1);
    atomicAdd(&hd[eidx[E + base + i] >> 7], 1);
  }
  __syncthreads();
  for (int i = threadIdx.x; i < NBUK; i += 256) {
    histd[(long)blockIdx.x * NBUK + i] = hd[i];
    hists[(long)blockIdx.x * NBUK + i] = hs[i];
  }
}

// Both per-bucket scans in one launch: grid = 2*NBUK.
__global__ __launch_bounds__(256) void k_bscan2x(int* __restrict__ histd,
                                                 int* __restrict__ btd,
                                                 int* __restrict__ hists,
                                                 int* __restrict__ bts) {
  __shared__ int s[256];
  const int which = (blockIdx.x >= NBUK);
  const int j = which ? blockIdx.x - NBUK : blockIdx.x;
  int* hist = which ? hists : histd;
  int* btotal = which ? bts : btd;
  const int tid = threadIdx.x;
  int v = hist[(long)tid * NBUK + j];
  s[tid] = v;
  for (int off = 1; off < 256; off <<= 1) {
    __syncthreads();
    int x = (tid >= off) ? s[tid - off] : 0;
    __syncthreads();
    s[tid] += x;
  }
  hist[(long)tid * NBUK + j] = s[tid] - v;   // exclusive within bucket
  if (tid == 255) btotal[j] = s[255];
}

// Both bucket-total scans in one launch: grid = 2.
__global__ __launch_bounds__(256) void k_bktscan2x(const int* __restrict__ btd,
                                                   int* __restrict__ bexcl,
                                                   const int* __restrict__ bts,
                                                   int* __restrict__ bexcl2,
                                                   int* __restrict__ rowptr) {
  __shared__ int s[256];
  const int* bt = blockIdx.x ? bts : btd;
  int* bx = blockIdx.x ? bexcl2 : bexcl;
  int tid = threadIdx.x;
  int base = tid * 4;
  int v0 = (base + 0 < NBUK) ? bt[base + 0] : 0;
  int v1 = (base + 1 < NBUK) ? bt[base + 1] : 0;
  int v2 = (base + 2 < NBUK) ? bt[base + 2] : 0;
  int v3 = (base + 3 < NBUK) ? bt[base + 3] : 0;
  int p0 = v0, p1 = p0 + v1, p2 = p1 + v2, p3 = p2 + v3;
  s[tid] = p3;
  for (int off = 1; off < 256; off <<= 1) {
    __syncthreads();
    int x = (tid >= off) ? s[tid - off] : 0;
    __syncthreads();
    s[tid] += x;
  }
  int excl = s[tid] - p3;
  if (base + 0 < NBUK) bx[base + 1] = excl + p0;
  if (base + 1 < NBUK) bx[base + 2] = excl + p1;
  if (base + 2 < NBUK) bx[base + 3] = excl + p2;
  if (base + 3 < NBUK) bx[base + 4] = excl + p3;
  if (tid == 0) { bx[0] = 0; if (blockIdx.x == 0) rowptr[N] = E; }
}

// Merged scatter: ONE edge pass writes BOTH orderings.
// ebuf (dst-order):  src(20b) | dstlow(7b)<<20
// ebuf2 (src-order): srclow(7b)<<17 | dst(17b)
__global__ __launch_bounds__(256) void k_scatter(const int* __restrict__ eidx,
                                                 const int* __restrict__ histd,
                                                 const int* __restrict__ bexcl,
                                                 const int* __restrict__ hists,
                                                 const int* __restrict__ bexcl2,
                                                 int* __restrict__ ebuf,
                                                 int* __restrict__ ebuf2) {
  __shared__ int hd[NBUK], hs[NBUK];
  for (int i = threadIdx.x; i < NBUK; i += 256) {
    hd[i] = bexcl[i] + histd[(long)blockIdx.x * NBUK + i];
    hs[i] = bexcl2[i] + hists[(long)blockIdx.x * NBUK + i];
  }
  __syncthreads();
  const long base = (long)blockIdx.x * EPB;
  for (int i = threadIdx.x; i < EPB; i += 256) {
    int s = eidx[base + i];
    int d = eidx[E + base + i];
    int pos = atomicAdd(&hd[d >> 7], 1);
    ebuf[pos] = s | ((d & 127) << 20);
    int pos2 = atomicAdd(&hs[s >> 7], 1);
    ebuf2[pos2] = ((s & 127) << 17) | d;
  }
}

// One block per dst-bucket: LDS counting sort -> rowptr/dinv/colsrc + xs16.
__global__ __launch_bounds__(256) void k_csr(const int* __restrict__ ebuf,
                                             const int* __restrict__ bexcl,
                                             const float* __restrict__ x,
                                             int* __restrict__ rowptr,
                                             float* __restrict__ dinv,
                                             int* __restrict__ colsrc,
                                             ushort_t* __restrict__ xs16) {
  __shared__ int deg[128], s[128], cur[128];
  __shared__ float dv[128];
  __shared__ int lout[BMAX];
  const int j = blockIdx.x, tid = threadIdx.x;
  const int e0 = bexcl[j], e1 = bexcl[j + 1];
  const int cnt = e1 - e0;
  if (tid < 128) deg[tid] = 0;
  __syncthreads();
  for (int i = tid; i < cnt; i += 256)
    atomicAdd(&deg[(ebuf[e0 + i] >> 20) & 127], 1);
  __syncthreads();
  int v = (tid < 128) ? deg[tid] : 0;
  if (tid < 128) s[tid] = v;
  for (int off = 1; off < 128; off <<= 1) {
    __syncthreads();
    int x2 = (tid < 128 && tid >= off) ? s[tid - off] : 0;
    __syncthreads();
    if (tid < 128) s[tid] += x2;
  }
  __syncthreads();
  if (tid < 128) {
    int ex = s[tid] - v;
    cur[tid] = ex;
    float d = rsqrtf((float)(1 + v));   // deg includes self-loop
    dv[tid] = d;
    int node = j * 128 + tid;
    if (node < N) {
      rowptr[node] = e0 + ex;
      dinv[node] = d;
    }
  }
  __syncthreads();
  if (cnt <= BMAX) {
    for (int i = tid; i < cnt; i += 256) {
      int p = ebuf[e0 + i];
      int pos = atomicAdd(&cur[(p >> 20) & 127], 1);
      lout[pos] = p & 0xFFFFF;
    }
    __syncthreads();
    for (int i = tid; i < cnt; i += 256) colsrc[e0 + i] = lout[i];
  } else {  // safety fallback
    for (int i = tid; i < cnt; i += 256) {
      int p = ebuf[e0 + i];
      int pos = atomicAdd(&cur[(p >> 20) & 127], 1);
      colsrc[e0 + pos] = p & 0xFFFFF;
    }
  }
  for (int idx = tid; idx < 128 * IND; idx += 256) {
    int n = idx / IND;
    long node = (long)j * 128 + n;
    if (node < N)
      xs16[node * IND + idx % IND] = f2bf(x[node * IND + idx % IND] * dv[n]);
  }
}

// ---------------- layer 1: fused 20-dim gather + MFMA conv1 + LN + ReLU ----------------

// A-tile: 16 nodes x K=64 (k<20: gathered aggx, 32<=k<52: bf16(x), else 0).
constexpr int ASTR = 72;    // bf16 A stride
constexpr int CSTR = 132;   // fp32 C stride

__global__ __launch_bounds__(256) void k_layer1(const ushort_t* __restrict__ xs16,
                                                const float* __restrict__ x,
                                                const int* __restrict__ rowptr,
                                                const int* __restrict__ colsrc,
                                                const ushort_t* __restrict__ w1pack,
                                                const float* __restrict__ b1,
                                                const float* __restrict__ resb,
                                                const float* __restrict__ g1,
                                                const float* __restrict__ bb1,
                                                const float* __restrict__ dinv,
                                                unsigned char* __restrict__ h8a) {
  __shared__ ushort_t A[16 * ASTR];   // 2.25 KB
  __shared__ float Cs[16 * CSTR];     // 8.25 KB
  const int tid = threadIdx.x;
  const long node0 = (long)blockIdx.x * 16;           // grid = N/16 exact
  // zero A, stage x into k in [32,52)
  for (int idx = tid; idx < 16 * ASTR; idx += 256) A[idx] = 0;
  __syncthreads();
  for (int idx = tid; idx < 16 * IND; idx += 256) {
    int n = idx / IND, k = idx % IND;
    A[n * ASTR + 32 + k] = f2bf(x[(node0 + n) * IND + k]);
  }
  // gather phase: 10 threads/node x 16 nodes = 160 active threads,
  // each owns 2 channels, serial over edges (unroll 4).
  if (tid < 160) {
    int n = tid / 10, cc = (tid % 10) * 2;
    long i = node0 + n;
    float di = dinv[i];
    uint_t u = *(const uint_t*)(xs16 + i * IND + cc);
    float a0 = bflo(u), a1 = bfhi(u);
    int e0 = rowptr[i], e1 = rowptr[i + 1];
#pragma unroll 4
    for (int e = e0; e < e1; ++e) {
      int s = colsrc[e];
      uint_t v = *(const uint_t*)(xs16 + (long)s * IND + cc);
      a0 += bflo(v); a1 += bfhi(v);
    }
    uint_t p0 = f2bf(a0 * di), p1 = f2bf(a1 * di);
    *(uint_t*)&A[n * ASTR + cc] = p0 | (p1 << 16);
  }
  __syncthreads();
  const int lane = tid & 63, w = tid >> 6;
  {
    const int arow = lane & 15, aq = lane >> 4;
    f32x4 acc0 = {0.f, 0.f, 0.f, 0.f}, acc1 = {0.f, 0.f, 0.f, 0.f};
    const int t0 = w * 2, t1 = t0 + 1;
#pragma unroll
    for (int kt = 0; kt < 2; ++kt) {
      bf16x8 af = *(const bf16x8*)&A[arow * ASTR + kt * 32 + aq * 8];
      bf16x8 b0 = *(const bf16x8*)&w1pack[(t0 * 2 + kt) * 512 + lane * 8];
      bf16x8 b1f = *(const bf16x8*)&w1pack[(t1 * 2 + kt) * 512 + lane * 8];
      acc0 = __builtin_amdgcn_mfma_f32_16x16x32_bf16(af, b0, acc0, 0, 0, 0);
      acc1 = __builtin_amdgcn_mfma_f32_16x16x32_bf16(af, b1f, acc1, 0, 0, 0);
    }
#pragma unroll
    for (int r = 0; r < 4; ++r) {
      Cs[(aq * 4 + r) * CSTR + t0 * 16 + arow] = acc0[r];
      Cs[(aq * 4 + r) * CSTR + t1 * 16 + arow] = acc1[r];
    }
  }
  __syncthreads();
  const int nidx = tid >> 5, col = (tid & 31) * 4;
  float4 bz = *(const float4*)&b1[col];
  float4 rz = *(const float4*)&resb[col];
  bz.x += rz.x; bz.y += rz.y; bz.z += rz.z; bz.w += rz.w;
  float4 gz = *(const float4*)&g1[col];
  float4 bbz = *(const float4*)&bb1[col];
#pragma unroll
  for (int m = 0; m < 2; ++m) {
    int nl = nidx + m * 8;
    long nm = node0 + nl;
    float4 o = *(const float4*)&Cs[nl * CSTR + col];
    o.x += bz.x; o.y += bz.y; o.z += bz.z; o.w += bz.w;
    float s = o.x + o.y + o.z + o.w;
    float q = o.x * o.x + o.y * o.y + o.z * o.z + o.w * o.w;
#pragma unroll
    for (int off = 1; off <= 16; off <<= 1) {
      s += __shfl_xor(s, off);
      q += __shfl_xor(q, off);
    }
    float mu = s * (1.f / 128.f);
    float var = q * (1.f / 128.f) - mu * mu;
    float rs = rsqrtf(var + 1e-5f);
    float y0 = fmaxf(fmaf((o.x - mu) * rs, gz.x, bbz.x), 0.f);
    float y1 = fmaxf(fmaf((o.y - mu) * rs, gz.y, bbz.y), 0.f);
    float y2 = fmaxf(fmaf((o.z - mu) * rs, gz.z, bbz.z), 0.f);
    float y3 = fmaxf(fmaf((o.w - mu) * rs, gz.w, bbz.w), 0.f);
    float di = dinv[nm];
    uint_t p = fp8pk2<false>(y0 * di, y1 * di, 0u);
    p = fp8pk2<true>(y2 * di, y3 * di, p);
    *(uint_t*)&h8a[nm * HID + col] = p;
  }
}

// ---------------- layer 2: fp8 gather + MFMA GEMM + LN + ReLU ----------------

constexpr int XSTR = 136;   // bf16 stride

__global__ __launch_bounds__(256) void k_layer2(const unsigned char* __restrict__ h8a,
                                                const float* __restrict__ dinv,
                                                const int* __restrict__ rowptr,
                                                const int* __restrict__ colsrc,
                                                const ushort_t* __restrict__ wpack,
                                                const float* __restrict__ bias,
                                                const float* __restrict__ g2,
                                                const float* __restrict__ bb2,
                                                unsigned char* __restrict__ h8b) {
  __shared__ ushort_t XsB[16 * XSTR];   // 4.25 KB bf16 gathered X
  __shared__ float Cs[16 * CSTR];       // 8.25 KB fp32 GEMM out
  const int tid = threadIdx.x;
  const long node0 = (long)blockIdx.x * 16;           // grid = N/16 exact
  const int lane = tid & 63, w = tid >> 6;
  // ---- phase 1: one ROW per 16-lane group; rows parallel; no reduce ----
  {
    const int grp = lane >> 4, l16 = lane & 15, c8 = l16 * 8;
    const long i = node0 + w * 4 + grp;
    const float di = dinv[i];
    float a0, a1, a2, a3, a4, a5, a6, a7;
    {   // self term (row already carries dinv[i])
      uint2 u = *(const uint2*)(h8a + i * HID + c8);
      FP8DEC8(u, a0, a1, a2, a3, a4, a5, a6, a7);
    }
    const int e0 = rowptr[i], e1 = rowptr[i + 1];
#pragma unroll 4
    for (int e = e0; e < e1; ++e) {
      int s = colsrc[e];
      uint2 u = *(const uint2*)(h8a + (long)s * HID + c8);
      float b0, b1, b2, b3, b4, b5, b6, b7;
      FP8DEC8(u, b0, b1, b2, b3, b4, b5, b6, b7);
      a0 += b0; a1 += b1; a2 += b2; a3 += b3;
      a4 += b4; a5 += b5; a6 += b6; a7 += b7;
    }
    uint_t p0 = (uint_t)f2bf(a0 * di) | ((uint_t)f2bf(a1 * di) << 16);
    uint_t p1 = (uint_t)f2bf(a2 * di) | ((uint_t)f2bf(a3 * di) << 16);
    uint_t p2 = (uint_t)f2bf(a4 * di) | ((uint_t)f2bf(a5 * di) << 16);
    uint_t p3 = (uint_t)f2bf(a6 * di) | ((uint_t)f2bf(a7 * di) << 16);
    *(uint4*)&XsB[(w * 4 + grp) * XSTR + c8] = make_uint4(p0, p1, p2, p3);
  }
  __syncthreads();
  // ---- phase 2: MFMA. Wave w covers n-tiles {2w, 2w+1}. ----
  {
    const int arow = lane & 15, aq = lane >> 4;
    f32x4 acc0 = {0.f, 0.f, 0.f, 0.f}, acc1 = {0.f, 0.f, 0.f, 0.f};
    const int t0 = w * 2, t1 = w * 2 + 1;
#pragma unroll
    for (int kt = 0; kt < 4; ++kt) {
      bf16x8 af = *(const bf16x8*)&XsB[arow * XSTR + kt * 32 + aq * 8];
      bf16x8 b0 = *(const bf16x8*)&wpack[(t0 * 4 + kt) * 512 + lane * 8];
      bf16x8 b1 = *(const bf16x8*)&wpack[(t1 * 4 + kt) * 512 + lane * 8];
      acc0 = __builtin_amdgcn_mfma_f32_16x16x32_bf16(af, b0, acc0, 0, 0, 0);
      acc1 = __builtin_amdgcn_mfma_f32_16x16x32_bf16(af, b1, acc1, 0, 0, 0);
    }
#pragma unroll
    for (int r = 0; r < 4; ++r) {
      Cs[(aq * 4 + r) * CSTR + t0 * 16 + arow] = acc0[r];
      Cs[(aq * 4 + r) * CSTR + t1 * 16 + arow] = acc1[r];
    }
  }
  __syncthreads();
  // ---- phase 3: bias + residual(fp8 h8a) + LN + ReLU + fp8 store ----
  const int nidx = tid >> 5;
  const int col = (tid & 31) * 4;
  float4 bz = *(const float4*)&bias[col];
  float4 gz = *(const float4*)&g2[col];
  float4 bbz = *(const float4*)&bb2[col];
#pragma unroll
  for (int m = 0; m < 2; ++m) {
    int nl = nidx + m * 8;
    long nm = node0 + nl;
    float di = dinv[nm];
    float rdi = 1.0f / di;
    uint_t ur = *(const uint_t*)&h8a[nm * HID + col];   // fp8 residual (L2-hot)
    float4 o = *(const float4*)&Cs[nl * CSTR + col];
    o.x += bz.x + fp8dec<0>(ur) * rdi;
    o.y += bz.y + fp8dec<1>(ur) * rdi;
    o.z += bz.z + fp8dec<2>(ur) * rdi;
    o.w += bz.w + fp8dec<3>(ur) * rdi;
    float s = o.x + o.y + o.z + o.w;
    float q = o.x * o.x + o.y * o.y + o.z * o.z + o.w * o.w;
#pragma unroll
    for (int off = 1; off <= 16; off <<= 1) {
      s += __shfl_xor(s, off);
      q += __shfl_xor(q, off);
    }
    float mu = s * (1.f / 128.f);
    float var = q * (1.f / 128.f) - mu * mu;
    float rs = rsqrtf(var + 1e-5f);
    float y0 = fmaxf(fmaf((o.x - mu) * rs, gz.x, bbz.x), 0.f);
    float y1 = fmaxf(fmaf((o.y - mu) * rs, gz.y, bbz.y), 0.f);
    float y2 = fmaxf(fmaf((o.z - mu) * rs, gz.z, bbz.z), 0.f);
    float y3 = fmaxf(fmaf((o.w - mu) * rs, gz.w, bbz.w), 0.f);
    uint_t p = fp8pk2<false>(y0 * di, y1 * di, 0u);
    p = fp8pk2<true>(y2 * di, y3 * di, p);
    *(uint_t*)&h8b[nm * HID + col] = p;
  }
}

// ---------------- layer 3: per-bucket dense pool GEMM ----------------

constexpr int RSTR8 = 136;  // fp8 row stride (bytes, 8B aligned)
constexpr int CP    = 132;  // fp32 row stride for C

__global__ __launch_bounds__(256) void k_pool3m(const unsigned char* __restrict__ h8b,
                                                const int* __restrict__ bexcl2,
                                                const int* __restrict__ ebuf2,
                                                const int* __restrict__ batch,
                                                const float* __restrict__ dinv,
                                                ushort_t* __restrict__ partial) {
  __shared__ float Cm[B * CP];            // 33.8 KB
  __shared__ unsigned char R8[128 * RSTR8];  // 17.4 KB raw fp8 rows
  const int j = blockIdx.x, tid = threadIdx.x;
  const long nbase = (long)j * 128;
  const int validRows = min(128, N - (int)nbase);
  for (int i = tid; i < B * CP; i += 256) Cm[i] = 0.f;
  for (int i = tid; i < 128 * (HID / 16); i += 256) {   // 16B per thread
    int s = i >> 3;
    int ch = (i & 7) * 16;
    uint4 pk = make_uint4(0u, 0u, 0u, 0u);
    if (s < validRows)
      pk = *(const uint4*)(h8b + (nbase + s) * HID + ch);
    *(uint4*)&R8[s * RSTR8 + ch] = pk;
  }
  __syncthreads();
  // edge-parallel C build (~8.5 iters/thread; batch/dinv L2-resident)
  const int e0 = bexcl2[j], e1 = bexcl2[j + 1];
  for (int e = e0 + tid; e < e1; e += 256) {
    int p = ebuf2[e];
    int s = (p >> 17) & 127;
    int d = p & 0x1FFFF;
    atomicAdd(&Cm[batch[d] * CP + s], dinv[d]);
  }
  for (int n = tid; n < validRows; n += 256) {
    long node = nbase + n;
    atomicAdd(&Cm[batch[node] * CP + n], dinv[node]);   // self term
  }
  __syncthreads();
  const int lane = tid & 63, wid = tid >> 6;
  const int m16 = lane & 15, quad = lane >> 4;
  f32x4 acc[4][2];
#pragma unroll
  for (int mt = 0; mt < 4; ++mt)
#pragma unroll
    for (int ntl = 0; ntl < 2; ++ntl) acc[mt][ntl] = (f32x4){0.f, 0.f, 0.f, 0.f};
#pragma unroll
  for (int kt = 0; kt < 4; ++kt) {
    union { ushort_t u[8]; bf16x8 v; } bf[2];
#pragma unroll
    for (int ntl = 0; ntl < 2; ++ntl) {
      int nt = wid * 2 + ntl;
#pragma unroll
      for (int jj = 0; jj < 8; ++jj) {
        uint_t byte = R8[(kt * 32 + quad * 8 + jj) * RSTR8 + nt * 16 + m16];
        bf[ntl].u[jj] = f2bf(fp8dec<0>(byte));   // fp8 -> bf16 exact
      }
    }
#pragma unroll
    for (int mt = 0; mt < 4; ++mt) {
      float4 c0 = *(const float4*)&Cm[(mt * 16 + m16) * CP + kt * 32 + quad * 8];
      float4 c1 = *(const float4*)&Cm[(mt * 16 + m16) * CP + kt * 32 + quad * 8 + 4];
      union { ushort_t u[8]; bf16x8 v; } af;
      af.u[0] = f2bf(c0.x); af.u[1] = f2bf(c0.y);
      af.u[2] = f2bf(c0.z); af.u[3] = f2bf(c0.w);
      af.u[4] = f2bf(c1.x); af.u[5] = f2bf(c1.y);
      af.u[6] = f2bf(c1.z); af.u[7] = f2bf(c1.w);
      acc[mt][0] = __builtin_amdgcn_mfma_f32_16x16x32_bf16(af.v, bf[0].v, acc[mt][0], 0, 0, 0);
      acc[mt][1] = __builtin_amdgcn_mfma_f32_16x16x32_bf16(af.v, bf[1].v, acc[mt][1], 0, 0, 0);
    }
  }
  // bf16 partial slab (plain coalesced stores)
  ushort_t* slab = partial + (long)j * (B * HID);
#pragma unroll
  for (int mt = 0; mt < 4; ++mt)
#pragma unroll
    for (int ntl = 0; ntl < 2; ++ntl)
#pragma unroll
      for (int r = 0; r < 4; ++r) {
        int g = mt * 16 + quad * 4 + r;
        int ch = (wid * 2 + ntl) * 16 + m16;
        slab[g * HID + ch] = f2bf(acc[mt][ntl][r]);
      }
}

__global__ __launch_bounds__(256) void k_pool_reduce(const ushort_t* __restrict__ partial,
                                                     float* __restrict__ pooled) {
  __shared__ float s[256];
  const int ol = threadIdx.x & 31, jl = threadIdx.x >> 5;
  const int o = blockIdx.x * 32 + ol;
  float acc = 0.f;
  for (int j = jl; j < NBUK; j += 8)
    acc += bflo((uint_t)partial[(long)j * (B * HID) + o]);
  s[threadIdx.x] = acc;
  __syncthreads();
  if (threadIdx.x < 32) {
    float a = s[threadIdx.x];
#pragma unroll
    for (int k = 1; k < 8; ++k) a += s[k * 32 + threadIdx.x];
    pooled[o] = a;
  }
}

// ---------------- final GEMM ----------------

__global__ __launch_bounds__(256) void k_final(const float* __restrict__ pooled,
                                               const int* __restrict__ starts,
                                               const float* __restrict__ W3,
                                               const float* __restrict__ b3,
                                               float* __restrict__ out) {
  __shared__ float p[HID];
  int g = blockIdx.x, tid = threadIdx.x;
  int len = starts[g + 1] - starts[g];
  float scale = 1.0f / fmaxf((float)len, 1.0f);
  if (tid < HID) p[tid] = pooled[g * HID + tid] * scale;
  __syncthreads();
  float a = b3[tid];
  for (int k = 0; k < HID; ++k) a = fmaf(p[k], W3[k * OUTD + tid], a);
  out[g * OUTD + tid] = a;
}

// ---------------- launch ----------------

extern "C" void kernel_launch(void* const* d_in, const int* in_sizes, int n_in,
                              void* d_out, int out_size, void* d_ws, size_t ws_size,
                              hipStream_t stream) {
  const float* x    = (const float*)d_in[0];
  const int*   eidx = (const int*)d_in[1];
  const int*   batch= (const int*)d_in[2];
  const float* W1   = (const float*)d_in[3];
  const float* b1   = (const float*)d_in[4];
  const float* W2   = (const float*)d_in[5];
  const float* b2   = (const float*)d_in[6];
  const float* W3   = (const float*)d_in[7];
  const float* b3   = (const float*)d_in[8];
  const float* resW = (const float*)d_in[9];
  const float* resb = (const float*)d_in[10];
  const float* g1   = (const float*)d_in[11];
  const float* bb1  = (const float*)d_in[12];
  const float* g2   = (const float*)d_in[13];
  const float* bb2  = (const float*)d_in[14];
  float* out = (float*)d_out;

  char* w = (char*)d_ws;
  size_t off = 0;
  auto alloc = [&](size_t bytes) {
    char* p = w + off;
    off = (off + bytes + 1023) & ~(size_t)1023;
    return p;
  };
  float* dinv   = (float*)alloc((size_t)N * 4);
  int*   rowptr = (int*)alloc((size_t)(N + 1) * 4);
  int*   colsrc = (int*)alloc((size_t)E * 4);
  int*   ebuf   = (int*)alloc((size_t)E * 4);
  int*   ebuf2  = (int*)alloc((size_t)E * 4);
  int*   hist   = (int*)alloc((size_t)GB * NBUK * 4);
  int*   hist2  = (int*)alloc((size_t)GB * NBUK * 4);
  int*   btotal = (int*)alloc((size_t)NBUK * 4);
  int*   btotal2= (int*)alloc((size_t)NBUK * 4);
  int*   bexcl  = (int*)alloc((size_t)(NBUK + 1) * 4);
  int*   bexcl2 = (int*)alloc((size_t)(NBUK + 1) * 4);
  int*   starts = (int*)alloc((size_t)(B + 1) * 4);
  float* pooled = (float*)alloc((size_t)B * HID * 4);
  ushort_t* xs16   = (ushort_t*)alloc((size_t)N * IND * 2);
  ushort_t* wpack  = (ushort_t*)alloc((size_t)HID * HID * 2);
  ushort_t* w1pack = (ushort_t*)alloc((size_t)8192 * 2);
  unsigned char* h8a = (unsigned char*)alloc((size_t)N * HID);
  unsigned char* h8b = (unsigned char*)alloc((size_t)N * HID);
  ushort_t* partial = (ushort_t*)alloc((size_t)NBUK * B * HID * 2);  // 12.8 MB

  // ---- prep: seg starts, weight packs, dual-order CSR build ----
  k_seg_starts<<<(N + 255) / 256, 256, 0, stream>>>(batch, starts);
  k_pack<<<96, 256, 0, stream>>>(W2, W1, resW, wpack, w1pack);
  k_hist<<<GB, 256, 0, stream>>>(eidx, hist, hist2);
  k_bscan2x<<<2 * NBUK, 256, 0, stream>>>(hist, btotal, hist2, btotal2);
  k_bktscan2x<<<2, 256, 0, stream>>>(btotal, bexcl, btotal2, bexcl2, rowptr);
  k_scatter<<<GB, 256, 0, stream>>>(eidx, hist, bexcl, hist2, bexcl2, ebuf, ebuf2);
  k_csr<<<NBUK, 256, 0, stream>>>(ebuf, bexcl, x, rowptr, dinv, colsrc, xs16);

  // ---- layer 1: fused gather + MFMA conv1 + LN1 + ReLU, fp8 out ----
  k_layer1<<<N / 16, 256, 0, stream>>>(xs16, x, rowptr, colsrc, w1pack,
                                       b1, resb, g1, bb1, dinv, h8a);

  // ---- layer 2: fp8 gather + MFMA GEMM + LN2 + ReLU, fp8 out ----
  k_layer2<<<N / 16, 256, 0, stream>>>(h8a, dinv, rowptr, colsrc,
                                       wpack, b2, g2, bb2, h8b);

  // ---- layer 3: dense per-bucket pool GEMM -> bf16 slabs -> reduce ----
  k_pool3m<<<NBUK, 256, 0, stream>>>(h8b, bexcl2, ebuf2, batch, dinv, partial);
  k_pool_reduce<<<(B * HID) / 32, 256, 0, stream>>>(partial, pooled);
  k_final<<<B, 256, 0, stream>>>(pooled, starts, W3, b3, out);
}